// Round 1
// baseline (2240.662 us; speedup 1.0000x reference)
//
#include <hip/hip_runtime.h>
#include <math.h>

// ---------- model constants ----------
#define NUM_GRAPHS 1024
#define NPG 9
#define NN 9216            // nodes
#define EE 73728           // edges
#define POSD 64

__device__ __forceinline__ float gelu_f(float x) {
    return 0.5f * x * (1.0f + erff(x * 0.70710678118654752f));
}

// ---------------------------------------------------------------------------
// Generic fp32 tiled GEMM: Cst[M,N] = act( A[M,K](lda) @ W[K,N](ldw)
//                                          + bias[n]*srow[m] + Cld[m,n] )
// Tile 64x64, 256 threads, 4x4 per thread, K-tile 16. Requires M%64==0,
// N%64==0, K%16==0 (true for every call in this model).
// ---------------------------------------------------------------------------
__global__ __launch_bounds__(256) void gemm_kernel(
    const float* __restrict__ A, int lda,
    const float* __restrict__ W, int ldw,
    const float* __restrict__ bias,
    const float* __restrict__ srow,
    const float* Cld, int ldc,
    float* Cst, int ldo,
    int K, int act)
{
    __shared__ float As[16][65];
    __shared__ float Bs[16][64];
    const int m0 = blockIdx.y * 64;
    const int n0 = blockIdx.x * 64;
    const int tid = threadIdx.x;
    const int tx = tid & 15, ty = tid >> 4;
    float acc[4][4] = {};
    const float* Ab = A + (size_t)m0 * lda;
    const float* Wb = W + n0;

    for (int k0 = 0; k0 < K; k0 += 16) {
#pragma unroll
        for (int i = 0; i < 4; i++) {
            int ii = tid + i * 256;
            int r = ii >> 4, c = ii & 15;
            As[c][r] = Ab[(size_t)r * lda + k0 + c];
            int rb = ii >> 6, cb = ii & 63;
            Bs[rb][cb] = Wb[(size_t)(k0 + rb) * ldw + cb];
        }
        __syncthreads();
#pragma unroll
        for (int kk = 0; kk < 16; kk++) {
            float a[4], b[4];
#pragma unroll
            for (int i = 0; i < 4; i++) a[i] = As[kk][ty * 4 + i];
#pragma unroll
            for (int j = 0; j < 4; j++) b[j] = Bs[kk][tx * 4 + j];
#pragma unroll
            for (int i = 0; i < 4; i++)
#pragma unroll
                for (int j = 0; j < 4; j++)
                    acc[i][j] += a[i] * b[j];
        }
        __syncthreads();
    }

#pragma unroll
    for (int i = 0; i < 4; i++) {
        int m = m0 + ty * 4 + i;
        float sv = srow ? srow[m] : 1.0f;
#pragma unroll
        for (int j = 0; j < 4; j++) {
            int n = n0 + tx * 4 + j;
            float v = acc[i][j];
            if (bias) v += bias[n] * sv;
            if (Cld) v += Cld[(size_t)m * ldc + n];
            if (act == 1) v = gelu_f(v);
            Cst[(size_t)m * ldo + n] = v;
        }
    }
}

// ---------------------------------------------------------------------------
// Per-node edge kernel: one 256-thread block per node n (in-edges 8n..8n+7).
//  logits_e = leaky_relu(Ad[n]+As[src_e]) . att2_w + att2_b   (bias att1_b in Ad)
//  attw     = softmax_8(logits) with PyG eps
//  G[n]     = sum_e attw_e * gelu(Pd[n] + Ps[src_e])          (bias pw1_b in Pd)
//  S[n]     = sum_e attw_e
// ---------------------------------------------------------------------------
__global__ __launch_bounds__(256) void edge_kernel(
    const float* __restrict__ Pd, const float* __restrict__ Ps,
    const float* __restrict__ Ad, const float* __restrict__ Asrc,
    const float* __restrict__ att2_w, const float* __restrict__ att2_b,
    const int* __restrict__ src_idx,
    float* __restrict__ G, float* __restrict__ S, int O)
{
    const int n = blockIdx.x;
    const int tid = threadIdx.x;
    const int lane = tid & 63, wid = tid >> 6;
    __shared__ float logits[8];
    __shared__ int ssrc[8];
    if (tid < 8) ssrc[tid] = src_idx[n * 8 + tid];
    __syncthreads();

    const float* adn = Ad + (size_t)n * O;
    const float b2 = att2_b[0];
    for (int e = wid; e < 8; e += 4) {
        const float* asn = Asrc + (size_t)ssrc[e] * O;
        float p = 0.f;
        for (int c = lane; c < O; c += 64) {
            float v = adn[c] + asn[c];
            v = (v > 0.f) ? v : 0.01f * v;
            p += v * att2_w[c];
        }
#pragma unroll
        for (int off = 32; off; off >>= 1) p += __shfl_down(p, off, 64);
        if (lane == 0) logits[e] = p + b2;
    }
    __syncthreads();

    float m = -INFINITY;
#pragma unroll
    for (int e = 0; e < 8; e++) m = fmaxf(m, logits[e]);
    float lw[8];
    float s = 0.f;
#pragma unroll
    for (int e = 0; e < 8; e++) { lw[e] = expf(logits[e] - m); s += lw[e]; }
    const float inv = 1.0f / (s + 1e-16f);
#pragma unroll
    for (int e = 0; e < 8; e++) lw[e] *= inv;

    const float* pdn = Pd + (size_t)n * O;
    for (int c = tid; c < O; c += 256) {
        float pd = pdn[c];
        float g = 0.f;
#pragma unroll
        for (int e = 0; e < 8; e++)
            g += lw[e] * gelu_f(pd + Ps[(size_t)ssrc[e] * O + c]);
        G[(size_t)n * O + c] = g;
    }
    if (tid == 0) S[n] = s * inv;
}

// ---------------------------------------------------------------------------
// LayerNorm over last dim O; writes to out[n*ldo + col_off + c]
// ---------------------------------------------------------------------------
__global__ __launch_bounds__(256) void ln_kernel(
    const float* __restrict__ H,
    const float* __restrict__ g, const float* __restrict__ b,
    float* __restrict__ out, int ldo, int col_off, int O)
{
    __shared__ float sm[4];
    const int n = blockIdx.x, tid = threadIdx.x;
    const int lane = tid & 63, wid = tid >> 6;
    const float* hr = H + (size_t)n * O;

    float sum = 0.f;
    for (int c = tid; c < O; c += 256) sum += hr[c];
#pragma unroll
    for (int off = 32; off; off >>= 1) sum += __shfl_down(sum, off, 64);
    if (lane == 0) sm[wid] = sum;
    __syncthreads();
    const float mu = (sm[0] + sm[1] + sm[2] + sm[3]) / (float)O;
    __syncthreads();

    float var = 0.f;
    for (int c = tid; c < O; c += 256) { float d = hr[c] - mu; var += d * d; }
#pragma unroll
    for (int off = 32; off; off >>= 1) var += __shfl_down(var, off, 64);
    if (lane == 0) sm[wid] = var;
    __syncthreads();
    const float rstd = rsqrtf((sm[0] + sm[1] + sm[2] + sm[3]) / (float)O + 1e-5f);

    for (int c = tid; c < O; c += 256)
        out[(size_t)n * ldo + col_off + c] = (hr[c] - mu) * rstd * g[c] + b[c];
}

// fill pos columns: dst[n*ld + col_off + c] = pos_table[(n%9)*64 + c]
__global__ void fill_pos_kernel(const float* __restrict__ pos_table,
                                float* __restrict__ dst, int ld, int col_off)
{
    int i = blockIdx.x * blockDim.x + threadIdx.x;
    if (i >= NN * POSD) return;
    int n = i >> 6, c = i & 63;
    dst[(size_t)n * ld + col_off + c] = pos_table[(n % NPG) * POSD + c];
}

// pooled[g, c] = sum_{k=0..8} h2[(g*9+k), c]   (O fixed 512)
__global__ void pool_kernel(const float* __restrict__ h2, float* __restrict__ pooled)
{
    int i = blockIdx.x * blockDim.x + threadIdx.x;
    if (i >= NUM_GRAPHS * 512) return;
    int gph = i >> 9, c = i & 511;
    const float* base = h2 + (size_t)gph * NPG * 512 + c;
    float s = 0.f;
#pragma unroll
    for (int k = 0; k < NPG; k++) s += base[(size_t)k * 512];
    pooled[i] = s;
}

// out[g] = hid[g,:256] . cls2_w + cls2_b
__global__ __launch_bounds__(64) void cls2_kernel(
    const float* __restrict__ hid, const float* __restrict__ w,
    const float* __restrict__ b, float* __restrict__ out)
{
    int gph = blockIdx.x, lane = threadIdx.x;
    float p = 0.f;
    for (int c = lane; c < 256; c += 64) p += hid[(size_t)gph * 256 + c] * w[c];
#pragma unroll
    for (int off = 32; off; off >>= 1) p += __shfl_down(p, off, 64);
    if (lane == 0) out[gph] = p + b[0];
}

// ---------------------------------------------------------------------------
// Host-side helpers
// ---------------------------------------------------------------------------
static inline void launch_gemm(hipStream_t st, int M, int N, int K,
                               const float* A, int lda, const float* W, int ldw,
                               const float* bias, const float* srow,
                               const float* Cld, int ldc,
                               float* Cst, int ldo, int act)
{
    dim3 grid(N / 64, M / 64);
    gemm_kernel<<<grid, dim3(256), 0, st>>>(A, lda, W, ldw, bias, srow, Cld, ldc, Cst, ldo, K, act);
}

struct LayerP {
    const float *pw1_w, *pw1_b, *pw2_w, *pw2_b, *att1_w, *att1_b, *att2_w, *att2_b,
                *upd_w, *upd_b, *ln_g, *ln_b, *skip_w, *skip_b;
};

static void run_layer(hipStream_t st, const float* ix, int I, int F, int O,
                      const LayerP& p, const int* srcIdx,
                      float* Pd, float* Ps, float* Ad, float* As_, float* G, float* S,
                      float* out, int ldo, int col_off)
{
    const int M = NN;
    // P_dst = ix @ pw1_w[0:I] + pw1_b ; P_src = ix @ pw1_w[I:2I]
    launch_gemm(st, M, O, I, ix, I, p.pw1_w, O, p.pw1_b, nullptr, nullptr, 0, Pd, O, 0);
    launch_gemm(st, M, O, I, ix, I, p.pw1_w + (size_t)I * O, O, nullptr, nullptr, nullptr, 0, Ps, O, 0);
    // A_dst = x @ att1_w[0:F] + att1_b + pos @ att1_w[2F:2F+64]
    launch_gemm(st, M, O, F, ix, I, p.att1_w, O, p.att1_b, nullptr, nullptr, 0, Ad, O, 0);
    launch_gemm(st, M, O, POSD, ix + F, I, p.att1_w + (size_t)2 * F * O, O,
                nullptr, nullptr, Ad, O, Ad, O, 0);
    // A_src = x @ att1_w[F:2F] + pos @ att1_w[2F+64:2F+128]
    launch_gemm(st, M, O, F, ix, I, p.att1_w + (size_t)F * O, O, nullptr, nullptr, nullptr, 0, As_, O, 0);
    launch_gemm(st, M, O, POSD, ix + F, I, p.att1_w + (size_t)(2 * F + POSD) * O, O,
                nullptr, nullptr, As_, O, As_, O, 0);
    // edge phase -> G, S
    edge_kernel<<<dim3(M), dim3(256), 0, st>>>(Pd, Ps, Ad, As_, p.att2_w, p.att2_b, srcIdx, G, S, O);
    // aggr = G @ pw2_w + S*pw2_b  -> Pd
    launch_gemm(st, M, O, O, G, O, p.pw2_w, O, p.pw2_b, S, nullptr, 0, Pd, O, 0);
    // upd = gelu(ix @ upd_w[0:I] + upd_b + aggr @ upd_w[I:I+O]) -> Ad
    launch_gemm(st, M, O, I, ix, I, p.upd_w, O, p.upd_b, nullptr, nullptr, 0, Ad, O, 0);
    launch_gemm(st, M, O, O, Pd, O, p.upd_w + (size_t)I * O, O, nullptr, nullptr, Ad, O, Ad, O, 1);
    // h = ix @ skip_w + skip_b + upd -> As_
    launch_gemm(st, M, O, I, ix, I, p.skip_w, O, p.skip_b, nullptr, Ad, O, As_, O, 0);
    // layernorm -> out (with ld/col offset so stage outputs concat in place)
    ln_kernel<<<dim3(M), dim3(256), 0, st>>>(As_, p.ln_g, p.ln_b, out, ldo, col_off, O);
}

extern "C" void kernel_launch(void* const* d_in, const int* in_sizes, int n_in,
                              void* d_out, int out_size, void* d_ws, size_t ws_size,
                              hipStream_t stream)
{
    (void)in_sizes; (void)n_in; (void)out_size; (void)ws_size;
    const float* feat_low   = (const float*)d_in[0];
    const float* feat_high  = (const float*)d_in[1];
    const int*   edge_index = (const int*)d_in[3];   // row0=src, row1=dst
    const float* pos_table  = (const float*)d_in[4];
    const float* proj_low_w  = (const float*)d_in[5];
    const float* proj_low_b  = (const float*)d_in[6];
    const float* proj_high_w = (const float*)d_in[7];
    const float* proj_high_b = (const float*)d_in[8];

    LayerP s1, s2;
    {
        const float** f = (const float**)&s1;
        for (int i = 0; i < 14; i++) f[i] = (const float*)d_in[9 + i];
        const float** f2 = (const float**)&s2;
        for (int i = 0; i < 14; i++) f2[i] = (const float*)d_in[23 + i];
    }
    const float* cls1_w = (const float*)d_in[37];
    const float* cls1_b = (const float*)d_in[38];
    const float* cls2_w = (const float*)d_in[39];
    const float* cls2_b = (const float*)d_in[40];
    float* out = (float*)d_out;

    // workspace layout (floats)
    float* ws = (float*)d_ws;
    float* ix1    = ws;                       // 9216*320
    float* ix2    = ix1 + (size_t)NN * 320;   // 9216*576
    float* Pd     = ix2 + (size_t)NN * 576;   // 9216*512
    float* Ps     = Pd + (size_t)NN * 512;
    float* Ad     = Ps + (size_t)NN * 512;
    float* As_    = Ad + (size_t)NN * 512;
    float* G      = As_ + (size_t)NN * 512;
    float* S      = G + (size_t)NN * 512;     // 9216
    float* pooled = S + NN;                   // 1024*512
    float* hid    = pooled + (size_t)NUM_GRAPHS * 512; // 1024*256

    const int* srcIdx = edge_index; // row 0

    // ---- stage 1, low ----
    {
        int tot = NN * POSD;
        fill_pos_kernel<<<dim3((tot + 255) / 256), dim3(256), 0, stream>>>(pos_table, ix1, 320, 256);
    }
    launch_gemm(stream, NN, 256, 512, feat_low, 512, proj_low_w, 256, proj_low_b,
                nullptr, nullptr, 0, ix1, 320, 0);
    run_layer(stream, ix1, 320, 256, 256, s1, srcIdx, Pd, Ps, Ad, As_, G, S, ix2, 576, 0);

    // ---- stage 1, high (same s1 params) ----
    launch_gemm(stream, NN, 256, 1024, feat_high, 1024, proj_high_w, 256, proj_high_b,
                nullptr, nullptr, 0, ix1, 320, 0);
    run_layer(stream, ix1, 320, 256, 256, s1, srcIdx, Pd, Ps, Ad, As_, G, S, ix2, 576, 256);

    // ---- stage 2 ----
    {
        int tot = NN * POSD;
        fill_pos_kernel<<<dim3((tot + 255) / 256), dim3(256), 0, stream>>>(pos_table, ix2, 576, 512);
    }
    // h2 -> Pd (free after layer's internal use; LN is last consumer of As_)
    run_layer(stream, ix2, 576, 512, 512, s2, srcIdx, Pd, Ps, Ad, As_, G, S, Pd, 512, 0);

    // ---- pool + classifier ----
    {
        int tot = NUM_GRAPHS * 512;
        pool_kernel<<<dim3((tot + 255) / 256), dim3(256), 0, stream>>>(Pd, pooled);
    }
    launch_gemm(stream, NUM_GRAPHS, 256, 512, pooled, 512, cls1_w, 256, cls1_b,
                nullptr, nullptr, 0, hid, 256, 1);
    cls2_kernel<<<dim3(NUM_GRAPHS), dim3(64), 0, stream>>>(hid, cls2_w, cls2_b, out);
}

// Round 2
// 1102.060 us; speedup vs baseline: 2.0332x; 2.0332x over previous
//
#include <hip/hip_runtime.h>
#include <math.h>

// ---------- model constants ----------
#define NUM_GRAPHS 1024
#define NPG 9
#define NN 9216            // nodes
#define POSD 64

typedef __attribute__((ext_vector_type(8))) short bf16x8;
typedef __attribute__((ext_vector_type(4))) float f32x4;

__device__ __forceinline__ float gelu_f(float x) {
    return 0.5f * x * (1.0f + erff(x * 0.70710678118654752f));
}

// fp32 -> bf16 (round to nearest even)
__device__ __forceinline__ ushort f2b(float v) {
    unsigned u = __float_as_uint(v);
    unsigned r = (u + 0x7fffu + ((u >> 16) & 1u)) >> 16;
    return (ushort)r;
}

// async global->LDS, 16B per lane; lds dest = uniform base + lane*16
__device__ __forceinline__ void gload16(const ushort* g, ushort* l) {
    __builtin_amdgcn_global_load_lds((const __attribute__((address_space(1))) void*)g,
                                     (__attribute__((address_space(3))) void*)l, 16, 0, 0);
}

// ---------------------------------------------------------------------------
// bf16 MFMA GEMM: C[M,N] = act( A[M,K]bf16 @ Wt[N,K]bf16^T
//                               + bias[n]*srow[m] + Cld[m,n] )
// Tile 128x64, 2 waves (each 64 rows x 64 cols), BK=64, 16x16x32 mfma.
// LDS layout: unit u = row*8 + (q ^ (row&7)), unit = 16B = 8 bf16 of k-run q.
// Requires M%128==0, N%64==0, K%64==0, lda%8==0 (all true in this model).
// ---------------------------------------------------------------------------
__global__ __launch_bounds__(128) void mgemm(
    const ushort* __restrict__ A, int lda,
    const ushort* __restrict__ Wt,
    const float* __restrict__ bias,
    const float* __restrict__ srow,
    const float* Cld, int ldc,
    float* outF, ushort* outB, int ldo,
    int K, int act)
{
    __shared__ ushort sA[128 * 64];
    __shared__ ushort sB[64 * 64];
    const int wave = threadIdx.x >> 6, lane = threadIdx.x & 63;
    const int m0 = blockIdx.y * 128, n0 = blockIdx.x * 64;

    f32x4 acc[4][4];
#pragma unroll
    for (int i = 0; i < 4; i++)
#pragma unroll
        for (int j = 0; j < 4; j++) acc[i][j] = (f32x4){0.f, 0.f, 0.f, 0.f};

    for (int k0 = 0; k0 < K; k0 += 64) {
        // stage A tile: 128x64 = 1024 units, 16 chunks of 64
#pragma unroll
        for (int i = 0; i < 8; i++) {
            int ca = wave * 8 + i;
            int u = ca * 64 + lane;
            int row = u >> 3, c = u & 7;
            int q = c ^ (row & 7);
            gload16(A + (size_t)(m0 + row) * lda + k0 + q * 8, sA + ca * 512);
        }
        // stage B tile: 64x64 = 512 units, 8 chunks
#pragma unroll
        for (int i = 0; i < 4; i++) {
            int cb = wave * 4 + i;
            int u = cb * 64 + lane;
            int row = u >> 3, c = u & 7;
            int q = c ^ (row & 7);
            gload16(Wt + (size_t)(n0 + row) * K + k0 + q * 8, sB + cb * 512);
        }
        __syncthreads();

#pragma unroll
        for (int kh = 0; kh < 2; kh++) {
            bf16x8 af[4], bfr[4];
            const int qg = kh * 4 + (lane >> 4);
#pragma unroll
            for (int bi = 0; bi < 4; bi++) {
                int row = wave * 64 + bi * 16 + (lane & 15);
                int c = qg ^ (row & 7);
                af[bi] = *(const bf16x8*)(sA + (row * 8 + c) * 8);
            }
#pragma unroll
            for (int bj = 0; bj < 4; bj++) {
                int row = bj * 16 + (lane & 15);
                int c = qg ^ (row & 7);
                bfr[bj] = *(const bf16x8*)(sB + (row * 8 + c) * 8);
            }
#pragma unroll
            for (int bi = 0; bi < 4; bi++)
#pragma unroll
                for (int bj = 0; bj < 4; bj++)
                    acc[bi][bj] = __builtin_amdgcn_mfma_f32_16x16x32_bf16(
                        af[bi], bfr[bj], acc[bi][bj], 0, 0, 0);
        }
        __syncthreads();
    }

    // epilogue: C/D map col=lane&15, row=(lane>>4)*4+reg
#pragma unroll
    for (int bi = 0; bi < 4; bi++) {
#pragma unroll
        for (int r = 0; r < 4; r++) {
            int m = m0 + wave * 64 + bi * 16 + (lane >> 4) * 4 + r;
            float sv = srow ? srow[m] : 1.0f;
#pragma unroll
            for (int bj = 0; bj < 4; bj++) {
                int n = n0 + bj * 16 + (lane & 15);
                float v = acc[bi][bj][r];
                if (bias) v += bias[n] * sv;
                if (Cld) v += Cld[(size_t)m * ldc + n];
                if (act) v = gelu_f(v);
                if (outF) outF[(size_t)m * ldo + n] = v;
                if (outB) outB[(size_t)m * ldo + n] = f2b(v);
            }
        }
    }
}

// ---------------------------------------------------------------------------
// weight transpose+convert: 19 jobs, out[n*K+k] = bf16(src[rowmap(k)*N + n])
// rowmap(k) = k < split ? off0+k : off1+k-split
// ---------------------------------------------------------------------------
#define NJOBS 19
struct TJobsArg {
    const float* src[NJOBS];
    long dst[NJOBS];
    int K[NJOBS], N[NJOBS], split[NJOBS], off0[NJOBS], off1[NJOBS];
};

__global__ __launch_bounds__(256) void tw_kernel(TJobsArg ja, ushort* wbuf)
{
    int j = blockIdx.y;
    int K = ja.K[j], N = ja.N[j];
    int tk = K >> 5, tn = N >> 5;
    int t = blockIdx.x;
    if (t >= tk * tn) return;
    int kt = t % tk, nt = t / tk;
    const float* src = ja.src[j];
    ushort* out = wbuf + ja.dst[j];
    __shared__ float L[32][33];
    int r = threadIdx.x >> 5, c = threadIdx.x & 31;
#pragma unroll
    for (int rr = 0; rr < 4; rr++) {
        int k = kt * 32 + rr * 8 + r;
        int srow = (k < ja.split[j]) ? ja.off0[j] + k : ja.off1[j] + k - ja.split[j];
        L[rr * 8 + r][c] = src[(size_t)srow * N + nt * 32 + c];
    }
    __syncthreads();
#pragma unroll
    for (int rr = 0; rr < 4; rr++) {
        int n = nt * 32 + rr * 8 + r;
        out[(size_t)n * K + kt * 32 + c] = f2b(L[c][rr * 8 + r]);
    }
}

// fp32 -> bf16 bulk convert (n % 4 == 0)
__global__ void f2b_kernel(const float* __restrict__ s, ushort* __restrict__ d, int n4)
{
    int i = blockIdx.x * blockDim.x + threadIdx.x;
    if (i >= n4) return;
    float4 v = ((const float4*)s)[i];
    ushort4 o;
    o.x = f2b(v.x); o.y = f2b(v.y); o.z = f2b(v.z); o.w = f2b(v.w);
    ((ushort4*)d)[i] = o;
}

// ---------------------------------------------------------------------------
// Per-node edge kernel (fp32 in, G bf16 out)
// ---------------------------------------------------------------------------
__global__ __launch_bounds__(256) void edge_kernel(
    const float* __restrict__ Pd, const float* __restrict__ Ps,
    const float* __restrict__ Ad, const float* __restrict__ Asrc,
    const float* __restrict__ att2_w, const float* __restrict__ att2_b,
    const int* __restrict__ src_idx,
    ushort* __restrict__ G, float* __restrict__ S, int O)
{
    const int n = blockIdx.x;
    const int tid = threadIdx.x;
    const int lane = tid & 63, wid = tid >> 6;
    __shared__ float logits[8];
    __shared__ int ssrc[8];
    if (tid < 8) ssrc[tid] = src_idx[n * 8 + tid];
    __syncthreads();

    const float* adn = Ad + (size_t)n * O;
    const float b2 = att2_b[0];
    for (int e = wid; e < 8; e += 4) {
        const float* asn = Asrc + (size_t)ssrc[e] * O;
        float p = 0.f;
        for (int c = lane; c < O; c += 64) {
            float v = adn[c] + asn[c];
            v = (v > 0.f) ? v : 0.01f * v;
            p += v * att2_w[c];
        }
#pragma unroll
        for (int off = 32; off; off >>= 1) p += __shfl_down(p, off, 64);
        if (lane == 0) logits[e] = p + b2;
    }
    __syncthreads();

    float m = -INFINITY;
#pragma unroll
    for (int e = 0; e < 8; e++) m = fmaxf(m, logits[e]);
    float lw[8];
    float s = 0.f;
#pragma unroll
    for (int e = 0; e < 8; e++) { lw[e] = expf(logits[e] - m); s += lw[e]; }
    const float inv = 1.0f / (s + 1e-16f);
#pragma unroll
    for (int e = 0; e < 8; e++) lw[e] *= inv;

    const float* pdn = Pd + (size_t)n * O;
    for (int c = tid; c < O; c += 256) {
        float pd = pdn[c];
        float g = 0.f;
#pragma unroll
        for (int e = 0; e < 8; e++)
            g += lw[e] * gelu_f(pd + Ps[(size_t)ssrc[e] * O + c]);
        G[(size_t)n * O + c] = f2b(g);
    }
    if (tid == 0) S[n] = s * inv;
}

// ---------------------------------------------------------------------------
// LayerNorm: optional bf16 out (ldoB/coloff) and optional fp32 out (ldoF)
// ---------------------------------------------------------------------------
__global__ __launch_bounds__(256) void ln_kernel(
    const float* __restrict__ H,
    const float* __restrict__ g, const float* __restrict__ b,
    ushort* outB, int ldoB, int coloff,
    float* outF, int ldoF, int O)
{
    __shared__ float sm[4];
    const int n = blockIdx.x, tid = threadIdx.x;
    const int lane = tid & 63, wid = tid >> 6;
    const float* hr = H + (size_t)n * O;

    float sum = 0.f;
    for (int c = tid; c < O; c += 256) sum += hr[c];
#pragma unroll
    for (int off = 32; off; off >>= 1) sum += __shfl_down(sum, off, 64);
    if (lane == 0) sm[wid] = sum;
    __syncthreads();
    const float mu = (sm[0] + sm[1] + sm[2] + sm[3]) / (float)O;
    __syncthreads();

    float var = 0.f;
    for (int c = tid; c < O; c += 256) { float d = hr[c] - mu; var += d * d; }
#pragma unroll
    for (int off = 32; off; off >>= 1) var += __shfl_down(var, off, 64);
    if (lane == 0) sm[wid] = var;
    __syncthreads();
    const float rstd = rsqrtf((sm[0] + sm[1] + sm[2] + sm[3]) / (float)O + 1e-5f);

    for (int c = tid; c < O; c += 256) {
        float v = (hr[c] - mu) * rstd * g[c] + b[c];
        if (outB) outB[(size_t)n * ldoB + coloff + c] = f2b(v);
        if (outF) outF[(size_t)n * ldoF + c] = v;
    }
}

// fill pos columns (bf16): dst[n*ld + off + c] = pos_table[(n%9)*64 + c]
__global__ void fill_pos_kernel(const float* __restrict__ pos_table,
                                ushort* __restrict__ dst, int ld, int coloff)
{
    int i = blockIdx.x * blockDim.x + threadIdx.x;
    if (i >= NN * POSD) return;
    int n = i >> 6, c = i & 63;
    dst[(size_t)n * ld + coloff + c] = f2b(pos_table[(n % NPG) * POSD + c]);
}

// pooled[g, c] = sum_k h2[g*9+k, c]  (fp32 in, bf16 out, O=512)
__global__ void pool_kernel(const float* __restrict__ h2, ushort* __restrict__ pooled)
{
    int i = blockIdx.x * blockDim.x + threadIdx.x;
    if (i >= NUM_GRAPHS * 512) return;
    int gph = i >> 9, c = i & 511;
    const float* base = h2 + (size_t)gph * NPG * 512 + c;
    float s = 0.f;
#pragma unroll
    for (int k = 0; k < NPG; k++) s += base[(size_t)k * 512];
    pooled[i] = f2b(s);
}

// out[g] = hid[g,:256] . cls2_w + cls2_b
__global__ __launch_bounds__(64) void cls2_kernel(
    const float* __restrict__ hid, const float* __restrict__ w,
    const float* __restrict__ b, float* __restrict__ out)
{
    int gph = blockIdx.x, lane = threadIdx.x;
    float p = 0.f;
    for (int c = lane; c < 256; c += 64) p += hid[(size_t)gph * 256 + c] * w[c];
#pragma unroll
    for (int off = 32; off; off >>= 1) p += __shfl_down(p, off, 64);
    if (lane == 0) out[gph] = p + b[0];
}

// ---------------------------------------------------------------------------
// Host side
// ---------------------------------------------------------------------------
static inline void mg(hipStream_t st, int M, int N, int K,
                      const ushort* A, int lda, const ushort* Wt,
                      const float* bias, const float* srow,
                      const float* Cld, int ldc,
                      float* outF, ushort* outB, int ldo, int act)
{
    dim3 grid(N / 64, M / 128);
    mgemm<<<grid, dim3(128), 0, st>>>(A, lda, Wt, bias, srow, Cld, ldc, outF, outB, ldo, K, act);
}

struct LayerB { const float *pw1_b, *pw2_b, *att1_b, *att2_w, *att2_b, *upd_b, *ln_g, *ln_b, *skip_b; };
struct LayerW { const ushort *pw1d, *pw1s, *attd, *atts, *pw2, *upda, *updb, *skip; };

static void run_layer(hipStream_t st, const ushort* ix, int I, int O,
                      const LayerW& w, const LayerB& p, const int* srcIdx,
                      float* Pd, float* Ps, float* Ad, float* Asb,
                      ushort* G, float* S,
                      ushort* lnOutB, int ldoB, int coloff, float* lnOutF)
{
    mg(st, NN, O, I, ix, I, w.pw1d, p.pw1_b, 0, 0, 0, Pd, 0, O, 0);
    mg(st, NN, O, I, ix, I, w.pw1s, 0, 0, 0, 0, Ps, 0, O, 0);
    mg(st, NN, O, I, ix, I, w.attd, p.att1_b, 0, 0, 0, Ad, 0, O, 0);
    mg(st, NN, O, I, ix, I, w.atts, 0, 0, 0, 0, Asb, 0, O, 0);
    edge_kernel<<<dim3(NN), dim3(256), 0, st>>>(Pd, Ps, Ad, Asb, p.att2_w, p.att2_b, srcIdx, G, S, O);
    ushort* aggr = (ushort*)Ps;  // Ps dead after edge; reuse as bf16 aggr
    mg(st, NN, O, O, G, O, w.pw2, p.pw2_b, S, 0, 0, 0, aggr, O, 0);
    mg(st, NN, O, I, ix, I, w.upda, p.upd_b, 0, 0, 0, Ad, 0, O, 0);
    mg(st, NN, O, O, aggr, O, w.updb, 0, 0, Ad, O, Ad, 0, O, 1);
    mg(st, NN, O, I, ix, I, w.skip, p.skip_b, 0, Ad, O, Asb, 0, O, 0);
    ln_kernel<<<dim3(NN), dim3(256), 0, st>>>(Asb, p.ln_g, p.ln_b, lnOutB, ldoB, coloff, lnOutF, O, O);
}

extern "C" void kernel_launch(void* const* d_in, const int* in_sizes, int n_in,
                              void* d_out, int out_size, void* d_ws, size_t ws_size,
                              hipStream_t stream)
{
    (void)in_sizes; (void)n_in; (void)out_size; (void)ws_size;
    const float* feat_low   = (const float*)d_in[0];
    const float* feat_high  = (const float*)d_in[1];
    const int*   edge_index = (const int*)d_in[3];   // row0 = src
    const float* pos_table  = (const float*)d_in[4];
    const float* proj_low_w  = (const float*)d_in[5];
    const float* proj_low_b  = (const float*)d_in[6];
    const float* proj_high_w = (const float*)d_in[7];
    const float* proj_high_b = (const float*)d_in[8];
    const float* cls1_b = (const float*)d_in[38];
    const float* cls2_w = (const float*)d_in[39];
    const float* cls2_b = (const float*)d_in[40];
    float* out = (float*)d_out;

    LayerB b1, b2;
    b1.pw1_b = (const float*)d_in[10]; b1.pw2_b = (const float*)d_in[12];
    b1.att1_b = (const float*)d_in[14]; b1.att2_w = (const float*)d_in[15];
    b1.att2_b = (const float*)d_in[16]; b1.upd_b = (const float*)d_in[18];
    b1.ln_g = (const float*)d_in[19]; b1.ln_b = (const float*)d_in[20];
    b1.skip_b = (const float*)d_in[22];
    b2.pw1_b = (const float*)d_in[24]; b2.pw2_b = (const float*)d_in[26];
    b2.att1_b = (const float*)d_in[28]; b2.att2_w = (const float*)d_in[29];
    b2.att2_b = (const float*)d_in[30]; b2.upd_b = (const float*)d_in[32];
    b2.ln_g = (const float*)d_in[33]; b2.ln_b = (const float*)d_in[34];
    b2.skip_b = (const float*)d_in[36];

    // ---- workspace layout (bytes, 256-aligned) ----
    char* base = (char*)d_ws;
    size_t cur = 0;
    auto alloc = [&](size_t bytes) { void* p = base + cur; cur += (bytes + 255) & ~(size_t)255; return p; };
    ushort* featB  = (ushort*)alloc((size_t)NN * 1024 * 2);  // shared: featL then featH
    ushort* ix1    = (ushort*)alloc((size_t)NN * 320 * 2);
    ushort* ix2    = (ushort*)alloc((size_t)NN * 576 * 2);
    float*  Pd     = (float*)alloc((size_t)NN * 512 * 4);    // also h2 (stage2 LN out)
    float*  Ps     = (float*)alloc((size_t)NN * 512 * 4);    // also aggr (bf16)
    float*  Ad     = (float*)alloc((size_t)NN * 512 * 4);
    float*  Asb    = (float*)alloc((size_t)NN * 512 * 4);
    ushort* G      = (ushort*)alloc((size_t)NN * 512 * 2);
    float*  S      = (float*)alloc((size_t)NN * 4);
    ushort* pooled = (ushort*)alloc((size_t)NUM_GRAPHS * 512 * 2);
    float*  hid    = (float*)alloc((size_t)NUM_GRAPHS * 256 * 4);
    ushort* wbuf   = (ushort*)alloc((size_t)3440640 * 2);

    // ---- weight transpose jobs ----
    TJobsArg ja;
    long woff[NJOBS];
    {
        const float* s1_pw1 = (const float*)d_in[9];
        const float* s1_pw2 = (const float*)d_in[11];
        const float* s1_att = (const float*)d_in[13];
        const float* s1_upd = (const float*)d_in[17];
        const float* s1_skp = (const float*)d_in[21];
        const float* s2_pw1 = (const float*)d_in[23];
        const float* s2_pw2 = (const float*)d_in[25];
        const float* s2_att = (const float*)d_in[27];
        const float* s2_upd = (const float*)d_in[31];
        const float* s2_skp = (const float*)d_in[35];
        const float* cls1_w = (const float*)d_in[37];
        struct J { const float* s; int K, N, split, o0, o1; };
        J js[NJOBS] = {
            {proj_low_w,  512, 256, 512, 0, 0},        // 0 projL
            {proj_high_w, 1024, 256, 1024, 0, 0},      // 1 projH
            {s1_pw1, 320, 256, 320, 0, 0},             // 2 s1 pw1 d
            {s1_pw1, 320, 256, 320, 320, 0},           // 3 s1 pw1 s
            {s1_att, 320, 256, 256, 0, 512},           // 4 s1 att d
            {s1_att, 320, 256, 256, 256, 576},         // 5 s1 att s
            {s1_pw2, 256, 256, 256, 0, 0},             // 6 s1 pw2
            {s1_upd, 320, 256, 320, 0, 0},             // 7 s1 upd a
            {s1_upd, 256, 256, 256, 320, 0},           // 8 s1 upd b
            {s1_skp, 320, 256, 320, 0, 0},             // 9 s1 skip
            {s2_pw1, 576, 512, 576, 0, 0},             // 10 s2 pw1 d
            {s2_pw1, 576, 512, 576, 576, 0},           // 11 s2 pw1 s
            {s2_att, 576, 512, 512, 0, 1024},          // 12 s2 att d
            {s2_att, 576, 512, 512, 512, 1088},        // 13 s2 att s
            {s2_pw2, 512, 512, 512, 0, 0},             // 14 s2 pw2
            {s2_upd, 576, 512, 576, 0, 0},             // 15 s2 upd a
            {s2_upd, 512, 512, 512, 576, 0},           // 16 s2 upd b
            {s2_skp, 576, 512, 576, 0, 0},             // 17 s2 skip
            {cls1_w, 512, 256, 512, 0, 0},             // 18 cls1
        };
        long off = 0;
        for (int i = 0; i < NJOBS; i++) {
            ja.src[i] = js[i].s; ja.K[i] = js[i].K; ja.N[i] = js[i].N;
            ja.split[i] = js[i].split; ja.off0[i] = js[i].o0; ja.off1[i] = js[i].o1;
            ja.dst[i] = off; woff[i] = off;
            off += (long)js[i].K * js[i].N;
        }
    }
    tw_kernel<<<dim3(288, NJOBS), dim3(256), 0, stream>>>(ja, wbuf);

    LayerW w1 = { wbuf + woff[2], wbuf + woff[3], wbuf + woff[4], wbuf + woff[5],
                  wbuf + woff[6], wbuf + woff[7], wbuf + woff[8], wbuf + woff[9] };
    LayerW w2 = { wbuf + woff[10], wbuf + woff[11], wbuf + woff[12], wbuf + woff[13],
                  wbuf + woff[14], wbuf + woff[15], wbuf + woff[16], wbuf + woff[17] };

    const int* srcIdx = edge_index;

    // pos columns (persist across both stage-1 runs)
    {
        int tot = NN * POSD, nb = (tot + 255) / 256;
        fill_pos_kernel<<<dim3(nb), dim3(256), 0, stream>>>(pos_table, ix1, 320, 256);
        fill_pos_kernel<<<dim3(nb), dim3(256), 0, stream>>>(pos_table, ix2, 576, 512);
    }

    // ---- stage 1, low ----
    f2b_kernel<<<dim3(NN * 512 / 4 / 256), dim3(256), 0, stream>>>(feat_low, featB, NN * 512 / 4);
    mg(stream, NN, 256, 512, featB, 512, wbuf + woff[0], proj_low_b, 0, 0, 0, 0, ix1, 320, 0);
    run_layer(stream, ix1, 320, 256, w1, b1, srcIdx, Pd, Ps, Ad, Asb, G, S, ix2, 576, 0, 0);

    // ---- stage 1, high ----
    f2b_kernel<<<dim3(NN * 1024 / 4 / 256), dim3(256), 0, stream>>>(feat_high, featB, NN * 1024 / 4);
    mg(stream, NN, 256, 1024, featB, 1024, wbuf + woff[1], proj_high_b, 0, 0, 0, 0, ix1, 320, 0);
    run_layer(stream, ix1, 320, 256, w1, b1, srcIdx, Pd, Ps, Ad, Asb, G, S, ix2, 576, 256, 0);

    // ---- stage 2 ---- (LN fp32 out -> h2 in Pd region)
    float* h2 = Pd;
    run_layer(stream, ix2, 576, 512, w2, b2, srcIdx, Pd, Ps, Ad, Asb, G, S, 0, 0, 0, h2);

    // ---- pool + classifier ----
    {
        int tot = NUM_GRAPHS * 512;
        pool_kernel<<<dim3((tot + 255) / 256), dim3(256), 0, stream>>>(h2, pooled);
    }
    mg(stream, NUM_GRAPHS, 256, 512, pooled, 512, wbuf + woff[18], cls1_b, 0, 0, 0, hid, 0, 256, 1);
    cls2_kernel<<<dim3(NUM_GRAPHS), dim3(64), 0, stream>>>(hid, cls2_w, cls2_b, out);
}

// Round 3
// 780.567 us; speedup vs baseline: 2.8706x; 1.4119x over previous
//
#include <hip/hip_runtime.h>
#include <math.h>

// ---------- model constants ----------
#define NUM_GRAPHS 1024
#define NPG 9
#define NN 9216            // nodes
#define POSD 64

typedef __attribute__((ext_vector_type(8))) short bf16x8;
typedef __attribute__((ext_vector_type(4))) float f32x4;

__device__ __forceinline__ float gelu_f(float x) {
    return 0.5f * x * (1.0f + erff(x * 0.70710678118654752f));
}
__device__ __forceinline__ ushort f2b(float v) {
    unsigned u = __float_as_uint(v);
    return (ushort)((u + 0x7fffu + ((u >> 16) & 1u)) >> 16);
}
__device__ __forceinline__ float b2f(ushort u) {
    return __uint_as_float(((unsigned)u) << 16);
}
__device__ __forceinline__ void gload16(const ushort* g, ushort* l) {
    __builtin_amdgcn_global_load_lds((const __attribute__((address_space(1))) void*)g,
                                     (__attribute__((address_space(3))) void*)l, 16, 0, 0);
}

// ---------------------------------------------------------------------------
// bf16 MFMA GEMM: C[M,N] = act( A[M,K]bf16 @ Wt[N,K]bf16^T + bias[n]*srow[m] )
// Tile 128x64, 2 waves, BK=64, 16x16x32 mfma, XOR-swizzled LDS.
// Requires M%128==0, N%64==0, K%64==0, lda%8==0.
// ---------------------------------------------------------------------------
__global__ __launch_bounds__(128) void mgemm(
    const ushort* __restrict__ A, int lda,
    const ushort* __restrict__ Wt,
    const float* __restrict__ bias,
    const float* __restrict__ srow,
    float* outF, ushort* outB, int ldo,
    int K, int act)
{
    __shared__ ushort sA[128 * 64];
    __shared__ ushort sB[64 * 64];
    const int wave = threadIdx.x >> 6, lane = threadIdx.x & 63;
    const int m0 = blockIdx.y * 128, n0 = blockIdx.x * 64;

    f32x4 acc[4][4];
#pragma unroll
    for (int i = 0; i < 4; i++)
#pragma unroll
        for (int j = 0; j < 4; j++) acc[i][j] = (f32x4){0.f, 0.f, 0.f, 0.f};

    for (int k0 = 0; k0 < K; k0 += 64) {
#pragma unroll
        for (int i = 0; i < 8; i++) {
            int ca = wave * 8 + i;
            int u = ca * 64 + lane;
            int row = u >> 3, c = u & 7;
            int q = c ^ (row & 7);
            gload16(A + (size_t)(m0 + row) * lda + k0 + q * 8, sA + ca * 512);
        }
#pragma unroll
        for (int i = 0; i < 4; i++) {
            int cb = wave * 4 + i;
            int u = cb * 64 + lane;
            int row = u >> 3, c = u & 7;
            int q = c ^ (row & 7);
            gload16(Wt + (size_t)(n0 + row) * K + k0 + q * 8, sB + cb * 512);
        }
        __syncthreads();

#pragma unroll
        for (int kh = 0; kh < 2; kh++) {
            bf16x8 af[4], bfr[4];
            const int qg = kh * 4 + (lane >> 4);
#pragma unroll
            for (int bi = 0; bi < 4; bi++) {
                int row = wave * 64 + bi * 16 + (lane & 15);
                int c = qg ^ (row & 7);
                af[bi] = *(const bf16x8*)(sA + (row * 8 + c) * 8);
            }
#pragma unroll
            for (int bj = 0; bj < 4; bj++) {
                int row = bj * 16 + (lane & 15);
                int c = qg ^ (row & 7);
                bfr[bj] = *(const bf16x8*)(sB + (row * 8 + c) * 8);
            }
#pragma unroll
            for (int bi = 0; bi < 4; bi++)
#pragma unroll
                for (int bj = 0; bj < 4; bj++)
                    acc[bi][bj] = __builtin_amdgcn_mfma_f32_16x16x32_bf16(
                        af[bi], bfr[bj], acc[bi][bj], 0, 0, 0);
        }
        __syncthreads();
    }

#pragma unroll
    for (int bi = 0; bi < 4; bi++) {
#pragma unroll
        for (int r = 0; r < 4; r++) {
            int m = m0 + wave * 64 + bi * 16 + (lane >> 4) * 4 + r;
            float sv = srow ? srow[m] : 1.0f;
#pragma unroll
            for (int bj = 0; bj < 4; bj++) {
                int n = n0 + bj * 16 + (lane & 15);
                float v = acc[bi][bj][r];
                if (bias) v += bias[n] * sv;
                if (act) v = gelu_f(v);
                if (outF) outF[(size_t)m * ldo + n] = v;
                if (outB) outB[(size_t)m * ldo + n] = f2b(v);
            }
        }
    }
}

// ---------------------------------------------------------------------------
// weight transpose+convert: out[n*K+k] = bf16(src[rowmap(k)*N + n])
// rowmap(k) = k < split ? off0+k : off1+k-split
// ---------------------------------------------------------------------------
#define NJOBS 16
struct TJobsArg {
    const float* src[NJOBS];
    long dst[NJOBS];
    int K[NJOBS], N[NJOBS], split[NJOBS], off0[NJOBS], off1[NJOBS];
};

__global__ __launch_bounds__(256) void tw_kernel(TJobsArg ja, ushort* wbuf)
{
    int j = blockIdx.y;
    int K = ja.K[j], N = ja.N[j];
    int tk = K >> 5, tn = N >> 5;
    int t = blockIdx.x;
    if (t >= tk * tn) return;
    int kt = t % tk, nt = t / tk;
    const float* src = ja.src[j];
    ushort* out = wbuf + ja.dst[j];
    __shared__ float L[32][33];
    int r = threadIdx.x >> 5, c = threadIdx.x & 31;
#pragma unroll
    for (int rr = 0; rr < 4; rr++) {
        int k = kt * 32 + rr * 8 + r;
        int srow = (k < ja.split[j]) ? ja.off0[j] + k : ja.off1[j] + k - ja.split[j];
        L[rr * 8 + r][c] = src[(size_t)srow * N + nt * 32 + c];
    }
    __syncthreads();
#pragma unroll
    for (int rr = 0; rr < 4; rr++) {
        int n = nt * 32 + rr * 8 + r;
        out[(size_t)n * K + kt * 32 + c] = f2b(L[c][rr * 8 + r]);
    }
}

// fp32 -> bf16 bulk convert (count % 4 == 0)
__global__ void f2b_kernel(const float* __restrict__ s, ushort* __restrict__ d, int n4)
{
    int i = blockIdx.x * blockDim.x + threadIdx.x;
    if (i >= n4) return;
    float4 v = ((const float4*)s)[i];
    ushort4 o;
    o.x = f2b(v.x); o.y = f2b(v.y); o.z = f2b(v.z); o.w = f2b(v.w);
    ((ushort4*)d)[i] = o;
}

// ---------------------------------------------------------------------------
// Graph-per-block edge kernel. PB row n: [Pd(O)|Ps(O)|Ad(O)|As(O)|skip(O)].
// Loads first 4O of the graph's 9 rows to LDS, computes 72 logits, softmax
// per dst, weighted gelu aggregation -> G (bf16), S.
// ---------------------------------------------------------------------------
__global__ __launch_bounds__(256) void edge_kernel(
    const ushort* __restrict__ PB, const float* __restrict__ att2_w,
    ushort* __restrict__ G, float* __restrict__ S, int O, int oshift)
{
    __shared__ ushort sPB[9 * 2048];   // max: 9 rows x 4*512
    __shared__ float logits[72];
    __shared__ float aw[72];
    const int g = blockIdx.x;
    const int tid = threadIdx.x, lane = tid & 63, wave = tid >> 6;
    const int O4 = O * 4, O5 = O * 5;
    const int cpr = O >> 7;             // 1KB chunks per row (4O*2B / 1024)
    const int total = 9 * cpr;
    const ushort* gbase = PB + (size_t)g * 9 * O5;

    for (int i = wave; i < total; i += 4) {
        int row = i / cpr, co = i - row * cpr;
        gload16(gbase + (size_t)row * O5 + co * 512 + lane * 8, sPB + i * 512);
    }
    __syncthreads();

    for (int e = wave; e < 72; e += 4) {
        int d = e >> 3, k = e & 7;
        int s = k + (k >= d);
        const ushort* ad = sPB + d * O4 + 2 * O;
        const ushort* as = sPB + s * O4 + 3 * O;
        float p = 0.f;
        for (int c = lane; c < O; c += 64) {
            float v = b2f(ad[c]) + b2f(as[c]);
            v = v > 0.f ? v : 0.01f * v;
            p += v * att2_w[c];
        }
#pragma unroll
        for (int off = 32; off; off >>= 1) p += __shfl_down(p, off, 64);
        if (lane == 0) logits[e] = p;     // att2_b cancels in softmax
    }
    __syncthreads();

    if (tid < 9) {
        float m = -INFINITY;
#pragma unroll
        for (int k = 0; k < 8; k++) m = fmaxf(m, logits[tid * 8 + k]);
        float s = 0.f, ee[8];
#pragma unroll
        for (int k = 0; k < 8; k++) { ee[k] = expf(logits[tid * 8 + k] - m); s += ee[k]; }
        float inv = 1.0f / (s + 1e-16f);
#pragma unroll
        for (int k = 0; k < 8; k++) aw[tid * 8 + k] = ee[k] * inv;
        S[g * 9 + tid] = s * inv;
    }
    __syncthreads();

    for (int idx = tid; idx < 9 * O; idx += 256) {
        int n = idx >> oshift, c = idx & (O - 1);
        float pd = b2f(sPB[n * O4 + c]);
        float acc = 0.f;
#pragma unroll
        for (int k = 0; k < 8; k++) {
            int s = k + (k >= n);
            acc += aw[n * 8 + k] * gelu_f(pd + b2f(sPB[s * O4 + O + c]));
        }
        G[(size_t)(g * 9 + n) * O + c] = f2b(acc);
    }
}

// ---------------------------------------------------------------------------
// LayerNorm of h = UD + skip_pre(bf16, from PB col 4O).
// outB optional bf16 (ldoB/coloff); outF optional fp32 (stride O, may = UD).
// ---------------------------------------------------------------------------
__global__ __launch_bounds__(256) void ln_kernel(
    const float* __restrict__ UD, const ushort* __restrict__ PBs, int ld5,
    const float* __restrict__ gw, const float* __restrict__ bw,
    ushort* outB, int ldoB, int coloff, float* outF, int O)
{
    __shared__ float sm[4];
    const int n = blockIdx.x, tid = threadIdx.x;
    const int lane = tid & 63, wid = tid >> 6;
    const float* ur = UD + (size_t)n * O;
    const ushort* sr = PBs + (size_t)n * ld5;

    float sum = 0.f;
    for (int c = tid; c < O; c += 256) sum += ur[c] + b2f(sr[c]);
#pragma unroll
    for (int off = 32; off; off >>= 1) sum += __shfl_down(sum, off, 64);
    if (lane == 0) sm[wid] = sum;
    __syncthreads();
    const float mu = (sm[0] + sm[1] + sm[2] + sm[3]) / (float)O;
    __syncthreads();

    float var = 0.f;
    for (int c = tid; c < O; c += 256) {
        float d = ur[c] + b2f(sr[c]) - mu; var += d * d;
    }
#pragma unroll
    for (int off = 32; off; off >>= 1) var += __shfl_down(var, off, 64);
    if (lane == 0) sm[wid] = var;
    __syncthreads();
    const float rstd = rsqrtf((sm[0] + sm[1] + sm[2] + sm[3]) / (float)O + 1e-5f);

    for (int c = tid; c < O; c += 256) {
        float v = (ur[c] + b2f(sr[c]) - mu) * rstd * gw[c] + bw[c];
        if (outB) outB[(size_t)n * ldoB + coloff + c] = f2b(v);
        if (outF) outF[(size_t)n * O + c] = v;   // may alias UD (same element)
    }
}

// ---------------------------------------------------------------------------
// prep: concat bias vectors + pos column fills
// ---------------------------------------------------------------------------
__global__ void prep_kernel(
    const float* __restrict__ pw1_b1, const float* __restrict__ att1_b1, const float* __restrict__ skip_b1,
    const float* __restrict__ pw1_b2, const float* __restrict__ att1_b2, const float* __restrict__ skip_b2,
    const float* __restrict__ pos_table,
    float* biasC1, float* biasC2, ushort* ixa1, ushort* ixa2)
{
    int i = blockIdx.x * 256 + threadIdx.x;
    if (i < 1280) {
        float v;
        if (i < 256) v = pw1_b1[i];
        else if (i < 512) v = 0.f;
        else if (i < 768) v = att1_b1[i - 512];
        else if (i < 1024) v = 0.f;
        else v = skip_b1[i - 1024];
        biasC1[i] = v;
        return;
    }
    i -= 1280;
    if (i < 2560) {
        float v;
        if (i < 512) v = pw1_b2[i];
        else if (i < 1024) v = 0.f;
        else if (i < 1536) v = att1_b2[i - 1024];
        else if (i < 2048) v = 0.f;
        else v = skip_b2[i - 2048];
        biasC2[i] = v;
        return;
    }
    i -= 2560;
    if (i < NN * POSD) {
        int n = i >> 6, c = i & 63;
        ixa1[(size_t)n * 576 + 256 + c] = f2b(pos_table[(n % NPG) * POSD + c]);
        return;
    }
    i -= NN * POSD;
    if (i < NN * POSD) {
        int n = i >> 6, c = i & 63;
        ixa2[(size_t)n * 1088 + 512 + c] = f2b(pos_table[(n % NPG) * POSD + c]);
    }
}

// ---------------------------------------------------------------------------
// head: pool(9 rows) + cls1 (gelu) + cls2, 4 graphs per block
// ---------------------------------------------------------------------------
__global__ __launch_bounds__(256) void head_kernel(
    const float* __restrict__ h2,
    const float* __restrict__ cls1_w, const float* __restrict__ cls1_b,
    const float* __restrict__ cls2_w, const float* __restrict__ cls2_b,
    float* __restrict__ out)
{
    __shared__ float pooled[4][512];
    __shared__ float hid[4][256];
    const int b = blockIdx.x, tid = threadIdx.x;

    for (int idx = tid; idx < 4 * 512; idx += 256) {
        int gi = idx >> 9, c = idx & 511;
        const float* base = h2 + (size_t)((b * 4 + gi) * 9) * 512 + c;
        float s = 0.f;
#pragma unroll
        for (int k = 0; k < NPG; k++) s += base[(size_t)k * 512];
        pooled[gi][c] = s;
    }
    __syncthreads();

    {
        float acc[4] = {0.f, 0.f, 0.f, 0.f};
        for (int c = 0; c < 512; c++) {
            float w = cls1_w[(size_t)c * 256 + tid];
#pragma unroll
            for (int gi = 0; gi < 4; gi++) acc[gi] += pooled[gi][c] * w;
        }
        float bb = cls1_b[tid];
#pragma unroll
        for (int gi = 0; gi < 4; gi++) hid[gi][tid] = gelu_f(acc[gi] + bb);
    }
    __syncthreads();

    {
        int gi = tid >> 6, lane = tid & 63;
        float p = 0.f;
#pragma unroll
        for (int i = 0; i < 4; i++) p += hid[gi][lane + 64 * i] * cls2_w[lane + 64 * i];
#pragma unroll
        for (int off = 32; off; off >>= 1) p += __shfl_down(p, off, 64);
        if (lane == 0) out[b * 4 + gi] = p + cls2_b[0];
    }
}

// ---------------------------------------------------------------------------
// Host side
// ---------------------------------------------------------------------------
static inline void mg(hipStream_t st, int M, int N, int K,
                      const ushort* A, int lda, const ushort* Wt,
                      const float* bias, const float* srow,
                      float* outF, ushort* outB, int ldo, int act)
{
    dim3 grid(N / 64, M / 128);
    mgemm<<<grid, dim3(128), 0, st>>>(A, lda, Wt, bias, srow, outF, outB, ldo, K, act);
}

struct LayerB { const float *pw2_b, *att2_w, *upd_b, *ln_g, *ln_b; };

// one GNN layer: big5 -> edge -> pw2 -> upd -> ln
static void run_layer(hipStream_t st, ushort* ixa, int I, int O, int oshift,
                      const ushort* wBig5, const ushort* wPw2, const ushort* wUpd,
                      const float* biasC, const LayerB& p,
                      ushort* PB, ushort* G, float* S, float* UD,
                      ushort* lnOutB, int ldoB, int coloff, float* lnOutF)
{
    const int IA = I + O;
    mg(st, NN, 5 * O, I, ixa, IA, wBig5, biasC, 0, 0, PB, 5 * O, 0);
    edge_kernel<<<dim3(NUM_GRAPHS), dim3(256), 0, st>>>(PB, p.att2_w, G, S, O, oshift);
    mg(st, NN, O, O, G, O, wPw2, p.pw2_b, S, 0, ixa + I, IA, 0);          // aggr
    mg(st, NN, O, IA, ixa, IA, wUpd, p.upd_b, 0, UD, 0, O, 1);            // gelu(upd)
    ln_kernel<<<dim3(NN), dim3(256), 0, st>>>(UD, PB + 4 * O, 5 * O,
                                              p.ln_g, p.ln_b, lnOutB, ldoB, coloff, lnOutF, O);
}

extern "C" void kernel_launch(void* const* d_in, const int* in_sizes, int n_in,
                              void* d_out, int out_size, void* d_ws, size_t ws_size,
                              hipStream_t stream)
{
    (void)in_sizes; (void)n_in; (void)out_size; (void)ws_size;
    const float* feat_low   = (const float*)d_in[0];
    const float* feat_high  = (const float*)d_in[1];
    const float* pos_table  = (const float*)d_in[4];
    const float* proj_low_w  = (const float*)d_in[5];
    const float* proj_low_b  = (const float*)d_in[6];
    const float* proj_high_w = (const float*)d_in[7];
    const float* proj_high_b = (const float*)d_in[8];
    const float* cls1_w = (const float*)d_in[37];
    const float* cls1_b = (const float*)d_in[38];
    const float* cls2_w = (const float*)d_in[39];
    const float* cls2_b = (const float*)d_in[40];
    float* out = (float*)d_out;

    LayerB b1, b2;
    b1.pw2_b = (const float*)d_in[12]; b1.att2_w = (const float*)d_in[15];
    b1.upd_b = (const float*)d_in[18]; b1.ln_g = (const float*)d_in[19]; b1.ln_b = (const float*)d_in[20];
    b2.pw2_b = (const float*)d_in[26]; b2.att2_w = (const float*)d_in[29];
    b2.upd_b = (const float*)d_in[32]; b2.ln_g = (const float*)d_in[33]; b2.ln_b = (const float*)d_in[34];

    // ---- workspace layout (256B aligned) ----
    char* base = (char*)d_ws;
    size_t cur = 0;
    auto alloc = [&](size_t bytes) { void* p = base + cur; cur += (bytes + 255) & ~(size_t)255; return p; };
    void*   PBreg = alloc((size_t)NN * 2560 * 2);   // PB (<=9216x2560 bf16); also featB alias
    ushort* PB    = (ushort*)PBreg;
    ushort* featB = (ushort*)PBreg;                 // feat bf16, dead before PB written
    ushort* ixa1  = (ushort*)alloc((size_t)NN * 576 * 2);
    ushort* ixa2  = (ushort*)alloc((size_t)NN * 1088 * 2);
    void*   UDreg = alloc((size_t)NN * 512 * 4);    // UD fp32; G bf16 alias (disjoint in time)
    float*  UD    = (float*)UDreg;
    ushort* G     = (ushort*)UDreg;
    float*  S     = (float*)alloc((size_t)NN * 4);
    float*  biasC1 = (float*)alloc(1280 * 4);
    float*  biasC2 = (float*)alloc(2560 * 4);
    ushort* wbuf  = (ushort*)alloc((size_t)3400000 * 2);

    // ---- weight transpose jobs ----
    TJobsArg ja;
    long woff[NJOBS];
    {
        const float* s1_pw1 = (const float*)d_in[9];
        const float* s1_pw2 = (const float*)d_in[11];
        const float* s1_att = (const float*)d_in[13];
        const float* s1_upd = (const float*)d_in[17];
        const float* s1_skp = (const float*)d_in[21];
        const float* s2_pw1 = (const float*)d_in[23];
        const float* s2_pw2 = (const float*)d_in[25];
        const float* s2_att = (const float*)d_in[27];
        const float* s2_upd = (const float*)d_in[31];
        const float* s2_skp = (const float*)d_in[35];
        struct J { const float* s; int K, N, split, o0, o1; };
        J js[NJOBS] = {
            {proj_low_w,  512, 256, 512, 0, 0},      // 0
            {proj_high_w, 1024, 256, 1024, 0, 0},    // 1
            {s1_pw1, 320, 256, 320, 0, 0},           // 2 big5-1: pw1d
            {s1_pw1, 320, 256, 320, 320, 0},         // 3 pw1s
            {s1_att, 320, 256, 256, 0, 512},         // 4 attd
            {s1_att, 320, 256, 256, 256, 576},       // 5 atts
            {s1_skp, 320, 256, 320, 0, 0},           // 6 skip
            {s1_pw2, 256, 256, 256, 0, 0},           // 7
            {s1_upd, 576, 256, 576, 0, 0},           // 8
            {s2_pw1, 576, 512, 576, 0, 0},           // 9 big5-2
            {s2_pw1, 576, 512, 576, 576, 0},         // 10
            {s2_att, 576, 512, 512, 0, 1024},        // 11
            {s2_att, 576, 512, 512, 512, 1088},      // 12
            {s2_skp, 576, 512, 576, 0, 0},           // 13
            {s2_pw2, 512, 512, 512, 0, 0},           // 14
            {s2_upd, 1088, 512, 1088, 0, 0},         // 15
        };
        long off = 0;
        for (int i = 0; i < NJOBS; i++) {
            ja.src[i] = js[i].s; ja.K[i] = js[i].K; ja.N[i] = js[i].N;
            ja.split[i] = js[i].split; ja.off0[i] = js[i].o0; ja.off1[i] = js[i].o1;
            ja.dst[i] = off; woff[i] = off;
            off += (long)js[i].K * js[i].N;
        }
    }
    tw_kernel<<<dim3(544, NJOBS), dim3(256), 0, stream>>>(ja, wbuf);

    // ---- prep (concat biases + pos fills) ----
    {
        int tot = 1280 + 2560 + 2 * NN * POSD;
        prep_kernel<<<dim3((tot + 255) / 256), dim3(256), 0, stream>>>(
            (const float*)d_in[10], (const float*)d_in[14], (const float*)d_in[22],
            (const float*)d_in[24], (const float*)d_in[28], (const float*)d_in[36],
            pos_table, biasC1, biasC2, ixa1, ixa2);
    }

    // ---- stage 1, low ----
    f2b_kernel<<<dim3(NN * 512 / 4 / 256), dim3(256), 0, stream>>>(feat_low, featB, NN * 512 / 4);
    mg(stream, NN, 256, 512, featB, 512, wbuf + woff[0], proj_low_b, 0, 0, ixa1, 576, 0);
    run_layer(stream, ixa1, 320, 256, 8, wbuf + woff[2], wbuf + woff[7], wbuf + woff[8],
              biasC1, b1, PB, G, S, UD, ixa2, 1088, 0, 0);

    // ---- stage 1, high (same s1 params) ----
    f2b_kernel<<<dim3(NN * 1024 / 4 / 256), dim3(256), 0, stream>>>(feat_high, featB, NN * 1024 / 4);
    mg(stream, NN, 256, 1024, featB, 1024, wbuf + woff[1], proj_high_b, 0, 0, ixa1, 576, 0);
    run_layer(stream, ixa1, 320, 256, 8, wbuf + woff[2], wbuf + woff[7], wbuf + woff[8],
              biasC1, b1, PB, G, S, UD, ixa2, 1088, 256, 0);

    // ---- stage 2 ---- (LN fp32 in-place into UD = h2)
    run_layer(stream, ixa2, 576, 512, 9, wbuf + woff[9], wbuf + woff[14], wbuf + woff[15],
              biasC2, b2, PB, G, S, UD, 0, 0, 0, UD);

    // ---- head ----
    head_kernel<<<dim3(NUM_GRAPHS / 4), dim3(256), 0, stream>>>(UD, cls1_w, cls1_b, cls2_w, cls2_b, out);
}

// Round 4
// 776.806 us; speedup vs baseline: 2.8845x; 1.0048x over previous
//
#include <hip/hip_runtime.h>
#include <math.h>

// ---------- model constants ----------
#define NUM_GRAPHS 1024
#define NPG 9
#define NN 9216            // nodes
#define POSD 64

typedef __attribute__((ext_vector_type(8))) short bf16x8;
typedef __attribute__((ext_vector_type(4))) float f32x4;

__device__ __forceinline__ float gelu_f(float x) {
    return 0.5f * x * (1.0f + erff(x * 0.70710678118654752f));
}
__device__ __forceinline__ ushort f2b(float v) {
    unsigned u = __float_as_uint(v);
    return (ushort)((u + 0x7fffu + ((u >> 16) & 1u)) >> 16);
}
__device__ __forceinline__ float b2f(ushort u) {
    return __uint_as_float(((unsigned)u) << 16);
}
__device__ __forceinline__ void gload16(const ushort* g, ushort* l) {
    __builtin_amdgcn_global_load_lds((const __attribute__((address_space(1))) void*)g,
                                     (__attribute__((address_space(3))) void*)l, 16, 0, 0);
}

// ---------------------------------------------------------------------------
// bf16 MFMA GEMM: C[M,N] = act( A[M,K]bf16 @ Wt[N,K]bf16^T
//                               + bias1[n] + bias2[n]*srow[m] )
// Tile 128x128, 4 waves (each 64x64), BK=64, 16x16x32 mfma, XOR-swizzled LDS.
// Requires M%128==0, N%128==0, K%64==0, lda%8==0.
// ---------------------------------------------------------------------------
__global__ __launch_bounds__(256) void mgemm(
    const ushort* __restrict__ A, int lda,
    const ushort* __restrict__ Wt,
    const float* __restrict__ bias1,
    const float* __restrict__ bias2,
    const float* __restrict__ srow,
    float* outF, ushort* outB, int ldo,
    int K, int act)
{
    __shared__ ushort sA[128 * 64];
    __shared__ ushort sB[128 * 64];
    const int wv = threadIdx.x >> 6, lane = threadIdx.x & 63;
    const int rh = wv & 1, ch = wv >> 1;
    const int m0 = blockIdx.y * 128, n0 = blockIdx.x * 128;

    f32x4 acc[4][4];
#pragma unroll
    for (int i = 0; i < 4; i++)
#pragma unroll
        for (int j = 0; j < 4; j++) acc[i][j] = (f32x4){0.f, 0.f, 0.f, 0.f};

    for (int k0 = 0; k0 < K; k0 += 64) {
#pragma unroll
        for (int i = 0; i < 4; i++) {
            int ca = wv * 4 + i;
            int u = ca * 64 + lane;
            int row = u >> 3, c = u & 7;
            int q = c ^ (row & 7);
            gload16(A + (size_t)(m0 + row) * lda + k0 + q * 8, sA + ca * 512);
            gload16(Wt + (size_t)(n0 + row) * K + k0 + q * 8, sB + ca * 512);
        }
        __syncthreads();

#pragma unroll
        for (int kh = 0; kh < 2; kh++) {
            const int qg = kh * 4 + (lane >> 4);
            bf16x8 af[4], bfr[4];
#pragma unroll
            for (int bi = 0; bi < 4; bi++) {
                int ar = rh * 64 + bi * 16 + (lane & 15);
                af[bi] = *(const bf16x8*)(sA + (ar * 8 + (qg ^ (ar & 7))) * 8);
            }
#pragma unroll
            for (int bj = 0; bj < 4; bj++) {
                int br = ch * 64 + bj * 16 + (lane & 15);
                bfr[bj] = *(const bf16x8*)(sB + (br * 8 + (qg ^ (br & 7))) * 8);
            }
#pragma unroll
            for (int bi = 0; bi < 4; bi++)
#pragma unroll
                for (int bj = 0; bj < 4; bj++)
                    acc[bi][bj] = __builtin_amdgcn_mfma_f32_16x16x32_bf16(
                        af[bi], bfr[bj], acc[bi][bj], 0, 0, 0);
        }
        __syncthreads();
    }

#pragma unroll
    for (int bi = 0; bi < 4; bi++) {
#pragma unroll
        for (int r = 0; r < 4; r++) {
            int m = m0 + rh * 64 + bi * 16 + (lane >> 4) * 4 + r;
            float sv = srow ? srow[m] : 1.0f;
#pragma unroll
            for (int bj = 0; bj < 4; bj++) {
                int n = n0 + ch * 64 + bj * 16 + (lane & 15);
                float v = acc[bi][bj][r];
                if (bias1) v += bias1[n];
                if (bias2) v += bias2[n] * sv;
                if (act) v = gelu_f(v);
                if (outF) outF[(size_t)m * ldo + n] = v;
                if (outB) outB[(size_t)m * ldo + n] = f2b(v);
            }
        }
    }
}

// ---------------------------------------------------------------------------
// weight transpose+convert: out[n*ldo + k] = bf16(src[rowmap(k)*N + n])
// rowmap(k) = k < split ? off0+k : off1+k-split
// ---------------------------------------------------------------------------
#define NJOBS 16
struct TJobsArg {
    const float* src[NJOBS];
    long dst[NJOBS];
    int K[NJOBS], N[NJOBS], split[NJOBS], off0[NJOBS], off1[NJOBS], ldo[NJOBS];
};

__global__ __launch_bounds__(256) void tw_kernel(TJobsArg ja, ushort* wbuf)
{
    int j = blockIdx.y;
    int K = ja.K[j], N = ja.N[j];
    int tk = K >> 5, tn = N >> 5;
    int t = blockIdx.x;
    if (t >= tk * tn) return;
    int kt = t % tk, nt = t / tk;
    const float* src = ja.src[j];
    ushort* out = wbuf + ja.dst[j];
    int ldo = ja.ldo[j];
    __shared__ float L[32][33];
    int r = threadIdx.x >> 5, c = threadIdx.x & 31;
#pragma unroll
    for (int rr = 0; rr < 4; rr++) {
        int k = kt * 32 + rr * 8 + r;
        int srow = (k < ja.split[j]) ? ja.off0[j] + k : ja.off1[j] + k - ja.split[j];
        L[rr * 8 + r][c] = src[(size_t)srow * N + nt * 32 + c];
    }
    __syncthreads();
#pragma unroll
    for (int rr = 0; rr < 4; rr++) {
        int n = nt * 32 + rr * 8 + r;
        out[(size_t)n * ldo + kt * 32 + c] = f2b(L[c][rr * 8 + r]);
    }
}

// fp32 -> bf16 bulk convert (count % 4 == 0)
__global__ void f2b_kernel(const float* __restrict__ s, ushort* __restrict__ d, int n4)
{
    int i = blockIdx.x * blockDim.x + threadIdx.x;
    if (i >= n4) return;
    float4 v = ((const float4*)s)[i];
    ushort4 o;
    o.x = f2b(v.x); o.y = f2b(v.y); o.z = f2b(v.z); o.w = f2b(v.w);
    ((ushort4*)d)[i] = o;
}

// ---------------------------------------------------------------------------
// Graph-per-block edge kernel. PB row n: [Pd(O)|Ps(O)|Ad(O)|As(O)|skip(O)].
// Loads first 4O of the graph's 9 rows to LDS, computes 72 logits, softmax
// per dst, weighted gelu aggregation -> Gout (bf16, row stride ldG), S.
// ---------------------------------------------------------------------------
__global__ __launch_bounds__(256) void edge_kernel(
    const ushort* __restrict__ PB, const float* __restrict__ att2_w,
    ushort* __restrict__ Gout, int ldG, float* __restrict__ S, int O, int oshift)
{
    __shared__ ushort sPB[9 * 2048];   // max: 9 rows x 4*512
    __shared__ float logits[72];
    __shared__ float aw[72];
    const int g = blockIdx.x;
    const int tid = threadIdx.x, lane = tid & 63, wave = tid >> 6;
    const int O4 = O * 4, O5 = O * 5;
    const int cpr = O >> 7;             // 1KB chunks per row (4O*2B / 1024)
    const int total = 9 * cpr;
    const ushort* gbase = PB + (size_t)g * 9 * O5;

    for (int i = wave; i < total; i += 4) {
        int row = i / cpr, co = i - row * cpr;
        gload16(gbase + (size_t)row * O5 + co * 512 + lane * 8, sPB + i * 512);
    }
    __syncthreads();

    for (int e = wave; e < 72; e += 4) {
        int d = e >> 3, k = e & 7;
        int s = k + (k >= d);
        const ushort* ad = sPB + d * O4 + 2 * O;
        const ushort* as = sPB + s * O4 + 3 * O;
        float p = 0.f;
        for (int c = lane; c < O; c += 64) {
            float v = b2f(ad[c]) + b2f(as[c]);
            v = v > 0.f ? v : 0.01f * v;
            p += v * att2_w[c];
        }
#pragma unroll
        for (int off = 32; off; off >>= 1) p += __shfl_down(p, off, 64);
        if (lane == 0) logits[e] = p;     // att2_b cancels in softmax
    }
    __syncthreads();

    if (tid < 9) {
        float m = -INFINITY;
#pragma unroll
        for (int k = 0; k < 8; k++) m = fmaxf(m, logits[tid * 8 + k]);
        float s = 0.f, ee[8];
#pragma unroll
        for (int k = 0; k < 8; k++) { ee[k] = expf(logits[tid * 8 + k] - m); s += ee[k]; }
        float inv = 1.0f / (s + 1e-16f);
#pragma unroll
        for (int k = 0; k < 8; k++) aw[tid * 8 + k] = ee[k] * inv;
        S[g * 9 + tid] = s * inv;
    }
    __syncthreads();

    for (int idx = tid; idx < 9 * O; idx += 256) {
        int n = idx >> oshift, c = idx & (O - 1);
        float pd = b2f(sPB[n * O4 + c]);
        float acc = 0.f;
#pragma unroll
        for (int k = 0; k < 8; k++) {
            int s = k + (k >= n);
            acc += aw[n * 8 + k] * gelu_f(pd + b2f(sPB[s * O4 + O + c]));
        }
        Gout[(size_t)(g * 9 + n) * ldG + c] = f2b(acc);
    }
}

// ---------------------------------------------------------------------------
// LayerNorm of h = UD + skip_pre(bf16, PB col 4O, stride 5O).
// outB optional bf16 (ldoB/coloff); outF optional fp32 (stride O, may = UD).
// ---------------------------------------------------------------------------
__global__ __launch_bounds__(256) void ln_kernel(
    const float* __restrict__ UD, const ushort* __restrict__ PBs, int ld5,
    const float* __restrict__ gw, const float* __restrict__ bw,
    ushort* outB, int ldoB, int coloff, float* outF, int O)
{
    __shared__ float sm[4];
    const int n = blockIdx.x, tid = threadIdx.x;
    const int lane = tid & 63, wid = tid >> 6;
    const float* ur = UD + (size_t)n * O;
    const ushort* sr = PBs + (size_t)n * ld5;

    float sum = 0.f;
    for (int c = tid; c < O; c += 256) sum += ur[c] + b2f(sr[c]);
#pragma unroll
    for (int off = 32; off; off >>= 1) sum += __shfl_down(sum, off, 64);
    if (lane == 0) sm[wid] = sum;
    __syncthreads();
    const float mu = (sm[0] + sm[1] + sm[2] + sm[3]) / (float)O;
    __syncthreads();

    float var = 0.f;
    for (int c = tid; c < O; c += 256) {
        float d = ur[c] + b2f(sr[c]) - mu; var += d * d;
    }
#pragma unroll
    for (int off = 32; off; off >>= 1) var += __shfl_down(var, off, 64);
    if (lane == 0) sm[wid] = var;
    __syncthreads();
    const float rstd = rsqrtf((sm[0] + sm[1] + sm[2] + sm[3]) / (float)O + 1e-5f);

    for (int c = tid; c < O; c += 256) {
        float v = (ur[c] + b2f(sr[c]) - mu) * rstd * gw[c] + bw[c];
        if (outB) outB[(size_t)n * ldoB + coloff + c] = f2b(v);
        if (outF) outF[(size_t)n * O + c] = v;   // may alias UD (same element)
    }
}

// ---------------------------------------------------------------------------
// prep: concat biases, pos fills, vb = pw2_b @ updb, plain-bf16 pw2 copies
// ---------------------------------------------------------------------------
__global__ void prep_kernel(
    const float* __restrict__ pw1_b1, const float* __restrict__ att1_b1, const float* __restrict__ skip_b1,
    const float* __restrict__ pw1_b2, const float* __restrict__ att1_b2, const float* __restrict__ skip_b2,
    const float* __restrict__ pos_table,
    const float* __restrict__ pw2_b1, const float* __restrict__ upd_w1,
    const float* __restrict__ pw2_b2, const float* __restrict__ upd_w2,
    const float* __restrict__ pw2_w1, const float* __restrict__ pw2_w2,
    float* biasC1, float* biasC2, ushort* ixa1, ushort* ixa2,
    float* vb1, float* vb2, ushort* pw2f1, ushort* pw2f2)
{
    int i = blockIdx.x * 256 + threadIdx.x;
    if (i < 1280) {
        float v;
        if (i < 256) v = pw1_b1[i];
        else if (i < 512) v = 0.f;
        else if (i < 768) v = att1_b1[i - 512];
        else if (i < 1024) v = 0.f;
        else v = skip_b1[i - 1024];
        biasC1[i] = v;
        return;
    }
    i -= 1280;
    if (i < 2560) {
        float v;
        if (i < 512) v = pw1_b2[i];
        else if (i < 1024) v = 0.f;
        else if (i < 1536) v = att1_b2[i - 1024];
        else if (i < 2048) v = 0.f;
        else v = skip_b2[i - 2048];
        biasC2[i] = v;
        return;
    }
    i -= 2560;
    if (i < NN * POSD) {
        int n = i >> 6, c = i & 63;
        ixa1[(size_t)n * 576 + 256 + c] = f2b(pos_table[(n % NPG) * POSD + c]);
        return;
    }
    i -= NN * POSD;
    if (i < NN * POSD) {
        int n = i >> 6, c = i & 63;
        ixa2[(size_t)n * 1088 + 512 + c] = f2b(pos_table[(n % NPG) * POSD + c]);
        return;
    }
    i -= NN * POSD;
    if (i < 256) {               // vb1[n] = sum_j pw2_b1[j] * upd_w1[(320+j)*256 + n]
        float a = 0.f;
        for (int j = 0; j < 256; j++) a += pw2_b1[j] * upd_w1[(size_t)(320 + j) * 256 + i];
        vb1[i] = a;
        return;
    }
    i -= 256;
    if (i < 512) {               // vb2[n] = sum_j pw2_b2[j] * upd_w2[(576+j)*512 + n]
        float a = 0.f;
        for (int j = 0; j < 512; j++) a += pw2_b2[j] * upd_w2[(size_t)(576 + j) * 512 + i];
        vb2[i] = a;
        return;
    }
    i -= 512;
    if (i < 256 * 256) { pw2f1[i] = f2b(pw2_w1[i]); return; }
    i -= 256 * 256;
    if (i < 512 * 512) { pw2f2[i] = f2b(pw2_w2[i]); return; }
}

// ---------------------------------------------------------------------------
// head: pool(9 rows) + cls1 (gelu) + cls2, 4 graphs per block
// ---------------------------------------------------------------------------
__global__ __launch_bounds__(256) void head_kernel(
    const float* __restrict__ h2,
    const float* __restrict__ cls1_w, const float* __restrict__ cls1_b,
    const float* __restrict__ cls2_w, const float* __restrict__ cls2_b,
    float* __restrict__ out)
{
    __shared__ float pooled[4][512];
    __shared__ float hid[4][256];
    const int b = blockIdx.x, tid = threadIdx.x;

    for (int idx = tid; idx < 4 * 512; idx += 256) {
        int gi = idx >> 9, c = idx & 511;
        const float* base = h2 + (size_t)((b * 4 + gi) * 9) * 512 + c;
        float s = 0.f;
#pragma unroll
        for (int k = 0; k < NPG; k++) s += base[(size_t)k * 512];
        pooled[gi][c] = s;
    }
    __syncthreads();

    {
        float acc[4] = {0.f, 0.f, 0.f, 0.f};
        for (int c = 0; c < 512; c++) {
            float w = cls1_w[(size_t)c * 256 + tid];
#pragma unroll
            for (int gi = 0; gi < 4; gi++) acc[gi] += pooled[gi][c] * w;
        }
        float bb = cls1_b[tid];
#pragma unroll
        for (int gi = 0; gi < 4; gi++) hid[gi][tid] = gelu_f(acc[gi] + bb);
    }
    __syncthreads();

    {
        int gi = tid >> 6, lane = tid & 63;
        float p = 0.f;
#pragma unroll
        for (int i = 0; i < 4; i++) p += hid[gi][lane + 64 * i] * cls2_w[lane + 64 * i];
#pragma unroll
        for (int off = 32; off; off >>= 1) p += __shfl_down(p, off, 64);
        if (lane == 0) out[b * 4 + gi] = p + cls2_b[0];
    }
}

// ---------------------------------------------------------------------------
// Host side
// ---------------------------------------------------------------------------
static inline void mg(hipStream_t st, int M, int N, int K,
                      const ushort* A, int lda, const ushort* Wt,
                      const float* bias1, const float* bias2, const float* srow,
                      float* outF, ushort* outB, int ldo, int act)
{
    dim3 grid(N / 128, M / 128);
    mgemm<<<grid, dim3(256), 0, st>>>(A, lda, Wt, bias1, bias2, srow, outF, outB, ldo, K, act);
}

struct LayerB { const float *att2_w, *upd_b, *ln_g, *ln_b; };

// one GNN layer: big5 -> edge(G into ixa) -> upd -> ln
static void run_layer(hipStream_t st, ushort* ixa, int I, int O, int oshift,
                      const ushort* wBig5, const ushort* wUpd,
                      const float* biasC, const float* vb, const LayerB& p,
                      ushort* PB, float* S, float* UD,
                      ushort* lnOutB, int ldoB, int coloff, float* lnOutF)
{
    const int IA = I + O;
    mg(st, NN, 5 * O, I, ixa, IA, wBig5, biasC, 0, 0, 0, PB, 5 * O, 0);
    edge_kernel<<<dim3(NUM_GRAPHS), dim3(256), 0, st>>>(PB, p.att2_w, ixa + I, IA, S, O, oshift);
    mg(st, NN, O, IA, ixa, IA, wUpd, p.upd_b, vb, S, UD, 0, O, 1);   // gelu(upd)
    ln_kernel<<<dim3(NN), dim3(256), 0, st>>>(UD, PB + 4 * O, 5 * O,
                                              p.ln_g, p.ln_b, lnOutB, ldoB, coloff, lnOutF, O);
}

extern "C" void kernel_launch(void* const* d_in, const int* in_sizes, int n_in,
                              void* d_out, int out_size, void* d_ws, size_t ws_size,
                              hipStream_t stream)
{
    (void)in_sizes; (void)n_in; (void)out_size; (void)ws_size;
    const float* feat_low   = (const float*)d_in[0];
    const float* feat_high  = (const float*)d_in[1];
    const float* pos_table  = (const float*)d_in[4];
    const float* proj_low_b  = (const float*)d_in[6];
    const float* proj_high_b = (const float*)d_in[8];
    const float* cls1_w = (const float*)d_in[37];
    const float* cls1_b = (const float*)d_in[38];
    const float* cls2_w = (const float*)d_in[39];
    const float* cls2_b = (const float*)d_in[40];
    float* out = (float*)d_out;

    LayerB b1, b2;
    b1.att2_w = (const float*)d_in[15]; b1.upd_b = (const float*)d_in[18];
    b1.ln_g = (const float*)d_in[19]; b1.ln_b = (const float*)d_in[20];
    b2.att2_w = (const float*)d_in[29]; b2.upd_b = (const float*)d_in[32];
    b2.ln_g = (const float*)d_in[33]; b2.ln_b = (const float*)d_in[34];

    // ---- workspace layout (256B aligned) ----
    char* base = (char*)d_ws;
    size_t cur = 0;
    auto alloc = [&](size_t bytes) { void* p = base + cur; cur += (bytes + 255) & ~(size_t)255; return p; };
    void*   PBreg = alloc((size_t)NN * 2560 * 2);   // PB; featB alias (disjoint in time)
    ushort* PB    = (ushort*)PBreg;
    ushort* featB = (ushort*)PBreg;
    ushort* ixa1  = (ushort*)alloc((size_t)NN * 576 * 2);
    ushort* ixa2  = (ushort*)alloc((size_t)NN * 1088 * 2);
    float*  UD    = (float*)alloc((size_t)NN * 512 * 4);
    float*  S     = (float*)alloc((size_t)NN * 4);
    float*  biasC1 = (float*)alloc(1280 * 4);
    float*  biasC2 = (float*)alloc(2560 * 4);
    float*  vb1   = (float*)alloc(256 * 4);
    float*  vb2   = (float*)alloc(512 * 4);
    ushort* wbuf  = (ushort*)alloc((size_t)3700000 * 2);

    // ---- weight transpose jobs ----
    // wbuf order: projL, projH, big5-1(pw1d,pw1s,attd,atts,skip), updW1, updbT1,
    //             big5-2(...), updW2, updbT2, pw2f1, pw2f2
    TJobsArg ja;
    long woff[18];
    {
        const float* s1_pw1 = (const float*)d_in[9];
        const float* s1_att = (const float*)d_in[13];
        const float* s1_upd = (const float*)d_in[17];
        const float* s1_skp = (const float*)d_in[21];
        const float* s2_pw1 = (const float*)d_in[23];
        const float* s2_att = (const float*)d_in[27];
        const float* s2_upd = (const float*)d_in[31];
        const float* s2_skp = (const float*)d_in[35];
        const float* proj_low_w  = (const float*)d_in[5];
        const float* proj_high_w = (const float*)d_in[7];
        struct J { const float* s; int K, N, split, o0, o1, ldo; long sz; };
        J js[NJOBS] = {
            {proj_low_w,  512, 256, 512, 0, 0, 512, 512L * 256},     // 0
            {proj_high_w, 1024, 256, 1024, 0, 0, 1024, 1024L * 256}, // 1
            {s1_pw1, 320, 256, 320, 0, 0, 320, 320L * 256},          // 2 big5-1
            {s1_pw1, 320, 256, 320, 320, 0, 320, 320L * 256},        // 3
            {s1_att, 320, 256, 256, 0, 512, 320, 320L * 256},        // 4
            {s1_att, 320, 256, 256, 256, 576, 320, 320L * 256},      // 5
            {s1_skp, 320, 256, 320, 0, 0, 320, 320L * 256},          // 6
            {s1_upd, 320, 256, 320, 0, 0, 576, 576L * 256},          // 7 updW1 (cols 0..320)
            {s1_upd, 256, 256, 256, 320, 0, 256, 256L * 256},        // 8 updbT1
            {s2_pw1, 576, 512, 576, 0, 0, 576, 576L * 512},          // 9 big5-2
            {s2_pw1, 576, 512, 576, 576, 0, 576, 576L * 512},        // 10
            {s2_att, 576, 512, 512, 0, 1024, 576, 576L * 512},       // 11
            {s2_att, 576, 512, 512, 512, 1088, 576, 576L * 512},     // 12
            {s2_skp, 576, 512, 576, 0, 0, 576, 576L * 512},          // 13
            {s2_upd, 576, 512, 576, 0, 0, 1088, 1088L * 512},        // 14 updW2 (cols 0..576)
            {s2_upd, 512, 512, 512, 576, 0, 512, 512L * 512},        // 15 updbT2
        };
        long off = 0;
        for (int i = 0; i < NJOBS; i++) {
            ja.src[i] = js[i].s; ja.K[i] = js[i].K; ja.N[i] = js[i].N;
            ja.split[i] = js[i].split; ja.off0[i] = js[i].o0; ja.off1[i] = js[i].o1;
            ja.ldo[i] = js[i].ldo;
            ja.dst[i] = off; woff[i] = off;
            off += js[i].sz;
        }
        woff[16] = off; off += 256L * 256;   // pw2f1
        woff[17] = off;                       // pw2f2
    }
    tw_kernel<<<dim3(288, NJOBS), dim3(256), 0, stream>>>(ja, wbuf);

    ushort* updW1  = wbuf + woff[7];
    ushort* updbT1 = wbuf + woff[8];
    ushort* updW2  = wbuf + woff[14];
    ushort* updbT2 = wbuf + woff[15];
    ushort* pw2f1  = wbuf + woff[16];
    ushort* pw2f2  = wbuf + woff[17];

    // ---- prep (biases, pos fills, vb, pw2 bf16 copies) ----
    {
        int tot = 1280 + 2560 + 2 * NN * POSD + 256 + 512 + 256 * 256 + 512 * 512;
        prep_kernel<<<dim3((tot + 255) / 256), dim3(256), 0, stream>>>(
            (const float*)d_in[10], (const float*)d_in[14], (const float*)d_in[22],
            (const float*)d_in[24], (const float*)d_in[28], (const float*)d_in[36],
            pos_table,
            (const float*)d_in[12], (const float*)d_in[17],
            (const float*)d_in[26], (const float*)d_in[31],
            (const float*)d_in[11], (const float*)d_in[25],
            biasC1, biasC2, ixa1, ixa2, vb1, vb2, pw2f1, pw2f2);
    }

    // ---- Wcomb = pw2 @ updb, written transposed into updW cols [I, I+O) ----
    mg(stream, 256, 256, 256, updbT1, 256, pw2f1, 0, 0, 0, 0, updW1 + 320, 576, 0);
    mg(stream, 512, 512, 512, updbT2, 512, pw2f2, 0, 0, 0, 0, updW2 + 576, 1088, 0);

    // ---- stage 1, low ----
    f2b_kernel<<<dim3(NN * 512 / 4 / 256), dim3(256), 0, stream>>>(feat_low, featB, NN * 512 / 4);
    mg(stream, NN, 256, 512, featB, 512, wbuf + woff[0], proj_low_b, 0, 0, 0, ixa1, 576, 0);
    run_layer(stream, ixa1, 320, 256, 8, wbuf + woff[2], updW1,
              biasC1, vb1, b1, PB, S, UD, ixa2, 1088, 0, 0);

    // ---- stage 1, high (same s1 params) ----
    f2b_kernel<<<dim3(NN * 1024 / 4 / 256), dim3(256), 0, stream>>>(feat_high, featB, NN * 1024 / 4);
    mg(stream, NN, 256, 1024, featB, 1024, wbuf + woff[1], proj_high_b, 0, 0, 0, ixa1, 576, 0);
    run_layer(stream, ixa1, 320, 256, 8, wbuf + woff[2], updW1,
              biasC1, vb1, b1, PB, S, UD, ixa2, 1088, 256, 0);

    // ---- stage 2 ---- (LN fp32 in-place into UD = h2)
    run_layer(stream, ixa2, 576, 512, 9, wbuf + woff[9], updW2,
              biasC2, vb2, b2, PB, S, UD, 0, 0, 0, UD);

    // ---- head ----
    head_kernel<<<dim3(NUM_GRAPHS / 4), dim3(256), 0, stream>>>(UD, cls1_w, cls1_b, cls2_w, cls2_b, out);
}

// Round 5
// 689.583 us; speedup vs baseline: 3.2493x; 1.1265x over previous
//
#include <hip/hip_runtime.h>
#include <math.h>

// ---------- model constants ----------
#define NUM_GRAPHS 1024
#define NPG 9
#define NN 9216            // nodes
#define NN2 18432          // batched stage-1 rows (low|high)
#define POSD 64

typedef __attribute__((ext_vector_type(8))) short bf16x8;
typedef __attribute__((ext_vector_type(4))) float f32x4;

__device__ __forceinline__ float gelu_f(float x) {
    return 0.5f * x * (1.0f + erff(x * 0.70710678118654752f));
}
__device__ __forceinline__ ushort f2b(float v) {
    unsigned u = __float_as_uint(v);
    return (ushort)((u + 0x7fffu + ((u >> 16) & 1u)) >> 16);
}
__device__ __forceinline__ float b2f(ushort u) {
    return __uint_as_float(((unsigned)u) << 16);
}
__device__ __forceinline__ void gload16(const ushort* g, ushort* l) {
    __builtin_amdgcn_global_load_lds((const __attribute__((address_space(1))) void*)g,
                                     (__attribute__((address_space(3))) void*)l, 16, 0, 0);
}

// ---------------------------------------------------------------------------
// bf16 MFMA GEMM, double-buffered prefetch K-loop.
// C[M,N] = act( A[M,K]bf16 @ Wt[N,K]bf16^T + bias1[n] + bias2[n]*srow[m] )
// Tile 128x128, 4 waves (each 64x64), BK=32, 16x16x32 mfma.
// LDS row layout: 4 chunks of 16B; chunk q stored at pos p=(q+(row>>1))&3
// (keeps ds_read_b128 <=2-way and global_load_lds wave-uniform dest).
// Requires M%128==0, N%128==0, K%32==0, lda%8==0.
// ---------------------------------------------------------------------------
__global__ __launch_bounds__(256, 3) void mgemm(
    const ushort* __restrict__ A, int lda,
    const ushort* __restrict__ Wt,
    const float* __restrict__ bias1,
    const float* __restrict__ bias2,
    const float* __restrict__ srow,
    float* outF, ushort* outB, int ldo,
    int K, int act)
{
    __shared__ ushort sA[2][128 * 32];
    __shared__ ushort sB[2][128 * 32];
    const int wv = threadIdx.x >> 6, lane = threadIdx.x & 63;
    const int rh = wv & 1, ch = wv >> 1;
    const int m0 = blockIdx.y * 128, n0 = blockIdx.x * 128;

    f32x4 acc[4][4];
#pragma unroll
    for (int i = 0; i < 4; i++)
#pragma unroll
        for (int j = 0; j < 4; j++) acc[i][j] = (f32x4){0.f, 0.f, 0.f, 0.f};

    const ushort* Ab = A + (size_t)m0 * lda;
    const ushort* Wb = Wt + (size_t)n0 * K;

    // stage one 16KB half-buffer pair: per wave 2 A-instr + 2 B-instr
    auto stage = [&](int b, int k0) {
#pragma unroll
        for (int i = 0; i < 2; i++) {
            int c = wv * 2 + i;
            int u = c * 64 + lane;
            int row = u >> 2, p = u & 3;
            int q = (p - (row >> 1)) & 3;
            gload16(Ab + (size_t)row * lda + k0 + q * 8, sA[b] + c * 512);
            gload16(Wb + (size_t)row * K + k0 + q * 8, sB[b] + c * 512);
        }
    };

    const int nsteps = K >> 5;
    stage(0, 0);
    int buf = 0;
    for (int s = 0; s < nsteps; s++) {
        __syncthreads();                       // vmcnt(0): prefetch for buf done
        if (s + 1 < nsteps) stage(buf ^ 1, (s + 1) << 5);
        const int qg = lane >> 4;
        bf16x8 af[4], bfr[4];
#pragma unroll
        for (int bi = 0; bi < 4; bi++) {
            int r = rh * 64 + bi * 16 + (lane & 15);
            af[bi] = *(const bf16x8*)(sA[buf] + (r * 4 + ((qg + (r >> 1)) & 3)) * 8);
        }
#pragma unroll
        for (int bj = 0; bj < 4; bj++) {
            int r = ch * 64 + bj * 16 + (lane & 15);
            bfr[bj] = *(const bf16x8*)(sB[buf] + (r * 4 + ((qg + (r >> 1)) & 3)) * 8);
        }
#pragma unroll
        for (int bi = 0; bi < 4; bi++)
#pragma unroll
            for (int bj = 0; bj < 4; bj++)
                acc[bi][bj] = __builtin_amdgcn_mfma_f32_16x16x32_bf16(
                    af[bi], bfr[bj], acc[bi][bj], 0, 0, 0);
        buf ^= 1;
    }

#pragma unroll
    for (int bi = 0; bi < 4; bi++) {
#pragma unroll
        for (int r = 0; r < 4; r++) {
            int m = m0 + rh * 64 + bi * 16 + (lane >> 4) * 4 + r;
            float sv = srow ? srow[m] : 1.0f;
#pragma unroll
            for (int bj = 0; bj < 4; bj++) {
                int n = n0 + ch * 64 + bj * 16 + (lane & 15);
                float v = acc[bi][bj][r];
                if (bias1) v += bias1[n];
                if (bias2) v += bias2[n] * sv;
                if (act) v = gelu_f(v);
                if (outF) outF[(size_t)m * ldo + n] = v;
                if (outB) outB[(size_t)m * ldo + n] = f2b(v);
            }
        }
    }
}

// ---------------------------------------------------------------------------
// weight transpose+convert: out[n*ldo + k] = bf16(src[rowmap(k)*N + n])
// rowmap(k) = k < split ? off0+k : off1+k-split
// ---------------------------------------------------------------------------
#define NJOBS 16
struct TJobsArg {
    const float* src[NJOBS];
    long dst[NJOBS];
    int K[NJOBS], N[NJOBS], split[NJOBS], off0[NJOBS], off1[NJOBS], ldo[NJOBS];
};

__global__ __launch_bounds__(256) void tw_kernel(TJobsArg ja, ushort* wbuf)
{
    int j = blockIdx.y;
    int K = ja.K[j], N = ja.N[j];
    int tk = K >> 5, tn = N >> 5;
    int t = blockIdx.x;
    if (t >= tk * tn) return;
    int kt = t % tk, nt = t / tk;
    const float* src = ja.src[j];
    ushort* out = wbuf + ja.dst[j];
    int ldo = ja.ldo[j];
    __shared__ float L[32][33];
    int r = threadIdx.x >> 5, c = threadIdx.x & 31;
#pragma unroll
    for (int rr = 0; rr < 4; rr++) {
        int k = kt * 32 + rr * 8 + r;
        int srow = (k < ja.split[j]) ? ja.off0[j] + k : ja.off1[j] + k - ja.split[j];
        L[rr * 8 + r][c] = src[(size_t)srow * N + nt * 32 + c];
    }
    __syncthreads();
#pragma unroll
    for (int rr = 0; rr < 4; rr++) {
        int n = nt * 32 + rr * 8 + r;
        out[(size_t)n * ldo + kt * 32 + c] = f2b(L[c][rr * 8 + r]);
    }
}

// fp32 -> bf16 bulk convert (count % 4 == 0)
__global__ void f2b_kernel(const float* __restrict__ s, ushort* __restrict__ d, int n4)
{
    int i = blockIdx.x * blockDim.x + threadIdx.x;
    if (i >= n4) return;
    float4 v = ((const float4*)s)[i];
    ushort4 o;
    o.x = f2b(v.x); o.y = f2b(v.y); o.z = f2b(v.z); o.w = f2b(v.w);
    ((ushort4*)d)[i] = o;
}

// ---------------------------------------------------------------------------
// Graph-per-block edge kernel. PB row n: [Pd(O)|Ps(O)|Ad(O)|As(O)|skip(O)].
// ---------------------------------------------------------------------------
__global__ __launch_bounds__(256) void edge_kernel(
    const ushort* __restrict__ PB, const float* __restrict__ att2_w,
    ushort* __restrict__ Gout, int ldG, float* __restrict__ S, int O, int oshift)
{
    __shared__ ushort sPB[9 * 2048];
    __shared__ float logits[72];
    __shared__ float aw[72];
    const int g = blockIdx.x;
    const int tid = threadIdx.x, lane = tid & 63, wave = tid >> 6;
    const int O4 = O * 4, O5 = O * 5;
    const int cpr = O >> 7;
    const int total = 9 * cpr;
    const ushort* gbase = PB + (size_t)g * 9 * O5;

    for (int i = wave; i < total; i += 4) {
        int row = i / cpr, co = i - row * cpr;
        gload16(gbase + (size_t)row * O5 + co * 512 + lane * 8, sPB + i * 512);
    }
    __syncthreads();

    for (int e = wave; e < 72; e += 4) {
        int d = e >> 3, k = e & 7;
        int s = k + (k >= d);
        const ushort* ad = sPB + d * O4 + 2 * O;
        const ushort* as = sPB + s * O4 + 3 * O;
        float p = 0.f;
        for (int c = lane; c < O; c += 64) {
            float v = b2f(ad[c]) + b2f(as[c]);
            v = v > 0.f ? v : 0.01f * v;
            p += v * att2_w[c];
        }
#pragma unroll
        for (int off = 32; off; off >>= 1) p += __shfl_down(p, off, 64);
        if (lane == 0) logits[e] = p;     // att2_b cancels in softmax
    }
    __syncthreads();

    if (tid < 9) {
        float m = -INFINITY;
#pragma unroll
        for (int k = 0; k < 8; k++) m = fmaxf(m, logits[tid * 8 + k]);
        float s = 0.f, ee[8];
#pragma unroll
        for (int k = 0; k < 8; k++) { ee[k] = expf(logits[tid * 8 + k] - m); s += ee[k]; }
        float inv = 1.0f / (s + 1e-16f);
#pragma unroll
        for (int k = 0; k < 8; k++) aw[tid * 8 + k] = ee[k] * inv;
        S[g * 9 + tid] = s * inv;
    }
    __syncthreads();

    for (int idx = tid; idx < 9 * O; idx += 256) {
        int n = idx >> oshift, c = idx & (O - 1);
        float pd = b2f(sPB[n * O4 + c]);
        float acc = 0.f;
#pragma unroll
        for (int k = 0; k < 8; k++) {
            int s = k + (k >= n);
            acc += aw[n * 8 + k] * gelu_f(pd + b2f(sPB[s * O4 + O + c]));
        }
        Gout[(size_t)(g * 9 + n) * ldG + c] = f2b(acc);
    }
}

// ---------------------------------------------------------------------------
// LayerNorm of h = UD + skip_pre(bf16, PB col 4O, stride ld5).
// Batched remap: rows >= rowsplit write out-row n-rowsplit, col += 256.
// ---------------------------------------------------------------------------
__global__ __launch_bounds__(256) void ln_kernel(
    const float* __restrict__ UD, const ushort* __restrict__ PBs, int ld5,
    const float* __restrict__ gw, const float* __restrict__ bw,
    ushort* outB, int ldoB, int rowsplit, float* outF, int O)
{
    __shared__ float sm[4];
    const int n = blockIdx.x, tid = threadIdx.x;
    const int lane = tid & 63, wid = tid >> 6;
    const float* ur = UD + (size_t)n * O;
    const ushort* sr = PBs + (size_t)n * ld5;

    float sum = 0.f;
    for (int c = tid; c < O; c += 256) sum += ur[c] + b2f(sr[c]);
#pragma unroll
    for (int off = 32; off; off >>= 1) sum += __shfl_down(sum, off, 64);
    if (lane == 0) sm[wid] = sum;
    __syncthreads();
    const float mu = (sm[0] + sm[1] + sm[2] + sm[3]) / (float)O;
    __syncthreads();

    float var = 0.f;
    for (int c = tid; c < O; c += 256) {
        float d = ur[c] + b2f(sr[c]) - mu; var += d * d;
    }
#pragma unroll
    for (int off = 32; off; off >>= 1) var += __shfl_down(var, off, 64);
    if (lane == 0) sm[wid] = var;
    __syncthreads();
    const float rstd = rsqrtf((sm[0] + sm[1] + sm[2] + sm[3]) / (float)O + 1e-5f);

    int orow = n, coloff = 0;
    if (n >= rowsplit) { orow = n - rowsplit; coloff = 256; }
    for (int c = tid; c < O; c += 256) {
        float v = (ur[c] + b2f(sr[c]) - mu) * rstd * gw[c] + bw[c];
        if (outB) outB[(size_t)orow * ldoB + coloff + c] = f2b(v);
        if (outF) outF[(size_t)n * O + c] = v;   // may alias UD
    }
}

// ---------------------------------------------------------------------------
// prep: concat biases, pos fills (ixa1 batched 18432 rows), vb, pw2 bf16
// ---------------------------------------------------------------------------
__global__ void prep_kernel(
    const float* __restrict__ pw1_b1, const float* __restrict__ att1_b1, const float* __restrict__ skip_b1,
    const float* __restrict__ pw1_b2, const float* __restrict__ att1_b2, const float* __restrict__ skip_b2,
    const float* __restrict__ pos_table,
    const float* __restrict__ pw2_b1, const float* __restrict__ upd_w1,
    const float* __restrict__ pw2_b2, const float* __restrict__ upd_w2,
    const float* __restrict__ pw2_w1, const float* __restrict__ pw2_w2,
    float* biasC1, float* biasC2, ushort* ixa1, ushort* ixa2,
    float* vb1, float* vb2, ushort* pw2f1, ushort* pw2f2)
{
    int i = blockIdx.x * 256 + threadIdx.x;
    if (i < 1280) {
        float v;
        if (i < 256) v = pw1_b1[i];
        else if (i < 512) v = 0.f;
        else if (i < 768) v = att1_b1[i - 512];
        else if (i < 1024) v = 0.f;
        else v = skip_b1[i - 1024];
        biasC1[i] = v;
        return;
    }
    i -= 1280;
    if (i < 2560) {
        float v;
        if (i < 512) v = pw1_b2[i];
        else if (i < 1024) v = 0.f;
        else if (i < 1536) v = att1_b2[i - 1024];
        else if (i < 2048) v = 0.f;
        else v = skip_b2[i - 2048];
        biasC2[i] = v;
        return;
    }
    i -= 2560;
    if (i < NN2 * POSD) {     // ixa1 pos (both halves; 9216%9==0 so n%9 ok)
        int n = i >> 6, c = i & 63;
        ixa1[(size_t)n * 576 + 256 + c] = f2b(pos_table[(n % NPG) * POSD + c]);
        return;
    }
    i -= NN2 * POSD;
    if (i < NN * POSD) {
        int n = i >> 6, c = i & 63;
        ixa2[(size_t)n * 1088 + 512 + c] = f2b(pos_table[(n % NPG) * POSD + c]);
        return;
    }
    i -= NN * POSD;
    if (i < 256) {
        float a = 0.f;
        for (int j = 0; j < 256; j++) a += pw2_b1[j] * upd_w1[(size_t)(320 + j) * 256 + i];
        vb1[i] = a;
        return;
    }
    i -= 256;
    if (i < 512) {
        float a = 0.f;
        for (int j = 0; j < 512; j++) a += pw2_b2[j] * upd_w2[(size_t)(576 + j) * 512 + i];
        vb2[i] = a;
        return;
    }
    i -= 512;
    if (i < 256 * 256) { pw2f1[i] = f2b(pw2_w1[i]); return; }
    i -= 256 * 256;
    if (i < 512 * 512) { pw2f2[i] = f2b(pw2_w2[i]); return; }
}

// ---------------------------------------------------------------------------
// head: pool(9 rows) + cls1 (gelu) + cls2, 4 graphs per block
// ---------------------------------------------------------------------------
__global__ __launch_bounds__(256) void head_kernel(
    const float* __restrict__ h2,
    const float* __restrict__ cls1_w, const float* __restrict__ cls1_b,
    const float* __restrict__ cls2_w, const float* __restrict__ cls2_b,
    float* __restrict__ out)
{
    __shared__ float pooled[4][512];
    __shared__ float hid[4][256];
    const int b = blockIdx.x, tid = threadIdx.x;

    for (int idx = tid; idx < 4 * 512; idx += 256) {
        int gi = idx >> 9, c = idx & 511;
        const float* base = h2 + (size_t)((b * 4 + gi) * 9) * 512 + c;
        float s = 0.f;
#pragma unroll
        for (int k = 0; k < NPG; k++) s += base[(size_t)k * 512];
        pooled[gi][c] = s;
    }
    __syncthreads();

    {
        float acc[4] = {0.f, 0.f, 0.f, 0.f};
        for (int c = 0; c < 512; c++) {
            float w = cls1_w[(size_t)c * 256 + tid];
#pragma unroll
            for (int gi = 0; gi < 4; gi++) acc[gi] += pooled[gi][c] * w;
        }
        float bb = cls1_b[tid];
#pragma unroll
        for (int gi = 0; gi < 4; gi++) hid[gi][tid] = gelu_f(acc[gi] + bb);
    }
    __syncthreads();

    {
        int gi = tid >> 6, lane = tid & 63;
        float p = 0.f;
#pragma unroll
        for (int i = 0; i < 4; i++) p += hid[gi][lane + 64 * i] * cls2_w[lane + 64 * i];
#pragma unroll
        for (int off = 32; off; off >>= 1) p += __shfl_down(p, off, 64);
        if (lane == 0) out[b * 4 + gi] = p + cls2_b[0];
    }
}

// ---------------------------------------------------------------------------
// Host side
// ---------------------------------------------------------------------------
static inline void mg(hipStream_t st, int M, int N, int K,
                      const ushort* A, int lda, const ushort* Wt,
                      const float* bias1, const float* bias2, const float* srow,
                      float* outF, ushort* outB, int ldo, int act)
{
    dim3 grid(N / 128, M / 128);
    mgemm<<<grid, dim3(256), 0, st>>>(A, lda, Wt, bias1, bias2, srow, outF, outB, ldo, K, act);
}

extern "C" void kernel_launch(void* const* d_in, const int* in_sizes, int n_in,
                              void* d_out, int out_size, void* d_ws, size_t ws_size,
                              hipStream_t stream)
{
    (void)in_sizes; (void)n_in; (void)out_size; (void)ws_size;
    const float* feat_low   = (const float*)d_in[0];
    const float* feat_high  = (const float*)d_in[1];
    const float* pos_table  = (const float*)d_in[4];
    const float* proj_low_b  = (const float*)d_in[6];
    const float* proj_high_b = (const float*)d_in[8];
    const float* cls1_w = (const float*)d_in[37];
    const float* cls1_b = (const float*)d_in[38];
    const float* cls2_w = (const float*)d_in[39];
    const float* cls2_b = (const float*)d_in[40];
    float* out = (float*)d_out;

    const float* att2_w1 = (const float*)d_in[15];
    const float* upd_b1  = (const float*)d_in[18];
    const float* ln_g1   = (const float*)d_in[19];
    const float* ln_b1   = (const float*)d_in[20];
    const float* att2_w2 = (const float*)d_in[29];
    const float* upd_b2  = (const float*)d_in[32];
    const float* ln_g2   = (const float*)d_in[33];
    const float* ln_b2   = (const float*)d_in[34];

    // ---- workspace layout (256B aligned) ----
    char* base = (char*)d_ws;
    size_t cur = 0;
    auto alloc = [&](size_t bytes) { void* p = base + cur; cur += (bytes + 255) & ~(size_t)255; return p; };
    void*   PBreg = alloc((size_t)NN2 * 1280 * 2);  // PB (stage1: 18432x1280, stage2: 9216x2560); featB alias
    ushort* PB    = (ushort*)PBreg;
    ushort* featB = (ushort*)PBreg;
    ushort* ixa1  = (ushort*)alloc((size_t)NN2 * 576 * 2);
    ushort* ixa2  = (ushort*)alloc((size_t)NN * 1088 * 2);
    float*  UD    = (float*)alloc((size_t)NN2 * 256 * 4); // == NN*512*4 for stage2
    float*  S     = (float*)alloc((size_t)NN2 * 4);
    float*  biasC1 = (float*)alloc(1280 * 4);
    float*  biasC2 = (float*)alloc(2560 * 4);
    float*  vb1   = (float*)alloc(256 * 4);
    float*  vb2   = (float*)alloc(512 * 4);
    ushort* wbuf  = (ushort*)alloc((size_t)3700000 * 2);

    // ---- weight transpose jobs ----
    TJobsArg ja;
    long woff[18];
    {
        const float* s1_pw1 = (const float*)d_in[9];
        const float* s1_att = (const float*)d_in[13];
        const float* s1_upd = (const float*)d_in[17];
        const float* s1_skp = (const float*)d_in[21];
        const float* s2_pw1 = (const float*)d_in[23];
        const float* s2_att = (const float*)d_in[27];
        const float* s2_upd = (const float*)d_in[31];
        const float* s2_skp = (const float*)d_in[35];
        const float* proj_low_w  = (const float*)d_in[5];
        const float* proj_high_w = (const float*)d_in[7];
        struct J { const float* s; int K, N, split, o0, o1, ldo; long sz; };
        J js[NJOBS] = {
            {proj_low_w,  512, 256, 512, 0, 0, 512, 512L * 256},     // 0
            {proj_high_w, 1024, 256, 1024, 0, 0, 1024, 1024L * 256}, // 1
            {s1_pw1, 320, 256, 320, 0, 0, 320, 320L * 256},          // 2 big5-1
            {s1_pw1, 320, 256, 320, 320, 0, 320, 320L * 256},        // 3
            {s1_att, 320, 256, 256, 0, 512, 320, 320L * 256},        // 4
            {s1_att, 320, 256, 256, 256, 576, 320, 320L * 256},      // 5
            {s1_skp, 320, 256, 320, 0, 0, 320, 320L * 256},          // 6
            {s1_upd, 320, 256, 320, 0, 0, 576, 576L * 256},          // 7 updW1
            {s1_upd, 256, 256, 256, 320, 0, 256, 256L * 256},        // 8 updbT1
            {s2_pw1, 576, 512, 576, 0, 0, 576, 576L * 512},          // 9 big5-2
            {s2_pw1, 576, 512, 576, 576, 0, 576, 576L * 512},        // 10
            {s2_att, 576, 512, 512, 0, 1024, 576, 576L * 512},       // 11
            {s2_att, 576, 512, 512, 512, 1088, 576, 576L * 512},     // 12
            {s2_skp, 576, 512, 576, 0, 0, 576, 576L * 512},          // 13
            {s2_upd, 576, 512, 576, 0, 0, 1088, 1088L * 512},        // 14 updW2
            {s2_upd, 512, 512, 512, 576, 0, 512, 512L * 512},        // 15 updbT2
        };
        long off = 0;
        for (int i = 0; i < NJOBS; i++) {
            ja.src[i] = js[i].s; ja.K[i] = js[i].K; ja.N[i] = js[i].N;
            ja.split[i] = js[i].split; ja.off0[i] = js[i].o0; ja.off1[i] = js[i].o1;
            ja.ldo[i] = js[i].ldo;
            ja.dst[i] = off; woff[i] = off;
            off += js[i].sz;
        }
        woff[16] = off; off += 256L * 256;   // pw2f1
        woff[17] = off;                       // pw2f2
    }
    tw_kernel<<<dim3(288, NJOBS), dim3(256), 0, stream>>>(ja, wbuf);

    ushort* updW1  = wbuf + woff[7];
    ushort* updbT1 = wbuf + woff[8];
    ushort* updW2  = wbuf + woff[14];
    ushort* updbT2 = wbuf + woff[15];
    ushort* pw2f1  = wbuf + woff[16];
    ushort* pw2f2  = wbuf + woff[17];

    // ---- prep ----
    {
        int tot = 1280 + 2560 + NN2 * POSD + NN * POSD + 256 + 512 + 256 * 256 + 512 * 512;
        prep_kernel<<<dim3((tot + 255) / 256), dim3(256), 0, stream>>>(
            (const float*)d_in[10], (const float*)d_in[14], (const float*)d_in[22],
            (const float*)d_in[24], (const float*)d_in[28], (const float*)d_in[36],
            pos_table,
            (const float*)d_in[12], (const float*)d_in[17],
            (const float*)d_in[26], (const float*)d_in[31],
            (const float*)d_in[11], (const float*)d_in[25],
            biasC1, biasC2, ixa1, ixa2, vb1, vb2, pw2f1, pw2f2);
    }

    // ---- Wcomb = pw2 @ updb, transposed into updW cols [I, I+O) ----
    mg(stream, 256, 256, 256, updbT1, 256, pw2f1, 0, 0, 0, 0, updW1 + 320, 576, 0);
    mg(stream, 512, 512, 512, updbT2, 512, pw2f2, 0, 0, 0, 0, updW2 + 576, 1088, 0);

    // ---- stage 1 (batched low|high, M = 18432) ----
    f2b_kernel<<<dim3(NN * 512 / 4 / 256), dim3(256), 0, stream>>>(feat_low, featB, NN * 512 / 4);
    f2b_kernel<<<dim3(NN * 1024 / 4 / 256), dim3(256), 0, stream>>>(
        feat_high, featB + (size_t)NN * 512, NN * 1024 / 4);
    mg(stream, NN, 256, 512, featB, 512, wbuf + woff[0], proj_low_b, 0, 0, 0, ixa1, 576, 0);
    mg(stream, NN, 256, 1024, featB + (size_t)NN * 512, 1024, wbuf + woff[1], proj_high_b, 0, 0,
       0, ixa1 + (size_t)NN * 576, 576, 0);

    mg(stream, NN2, 1280, 320, ixa1, 576, wbuf + woff[2], biasC1, 0, 0, 0, PB, 1280, 0);
    edge_kernel<<<dim3(2 * NUM_GRAPHS), dim3(256), 0, stream>>>(
        PB, att2_w1, ixa1 + 320, 576, S, 256, 8);
    mg(stream, NN2, 256, 576, ixa1, 576, updW1, upd_b1, vb1, S, UD, 0, 256, 1);
    ln_kernel<<<dim3(NN2), dim3(256), 0, stream>>>(UD, PB + 4 * 256, 1280,
                                                   ln_g1, ln_b1, ixa2, 1088, NN, 0, 256);

    // ---- stage 2 ----
    mg(stream, NN, 2560, 576, ixa2, 1088, wbuf + woff[9], biasC2, 0, 0, 0, PB, 2560, 0);
    edge_kernel<<<dim3(NUM_GRAPHS), dim3(256), 0, stream>>>(
        PB, att2_w2, ixa2 + 576, 1088, S, 512, 9);
    mg(stream, NN, 512, 1088, ixa2, 1088, updW2, upd_b2, vb2, S, UD, 0, 512, 1);
    ln_kernel<<<dim3(NN), dim3(256), 0, stream>>>(UD, PB + 4 * 512, 2560,
                                                  ln_g2, ln_b2, 0, 0, 1 << 30, UD, 512);

    // ---- head ----
    head_kernel<<<dim3(NUM_GRAPHS / 4), dim3(256), 0, stream>>>(UD, cls1_w, cls1_b, cls2_w, cls2_b, out);
}

// Round 6
// 672.668 us; speedup vs baseline: 3.3310x; 1.0251x over previous
//
#include <hip/hip_runtime.h>
#include <math.h>

// ---------- model constants ----------
#define NUM_GRAPHS 1024
#define NPG 9
#define NN 9216            // nodes
#define NN2 18432          // batched stage-1 rows (low|high)
#define POSD 64

typedef __attribute__((ext_vector_type(8))) short bf16x8;
typedef __attribute__((ext_vector_type(4))) float f32x4;

__device__ __forceinline__ float gelu_f(float x) {
    return 0.5f * x * (1.0f + erff(x * 0.70710678118654752f));
}
// fast gelu (tanh form), |err| <= ~3e-3 vs erf-gelu
__device__ __forceinline__ float gelu_fast(float x) {
    float y = 0.7978845608f * x * (1.0f + 0.044715f * x * x);
    float t = __expf(-2.0f * fabsf(y));
    float r = (1.0f - t) / (1.0f + t);
    r = copysignf(r, y);
    return 0.5f * x * (1.0f + r);
}
__device__ __forceinline__ ushort f2b(float v) {
    unsigned u = __float_as_uint(v);
    return (ushort)((u + 0x7fffu + ((u >> 16) & 1u)) >> 16);
}
__device__ __forceinline__ float b2f(ushort u) {
    return __uint_as_float(((unsigned)u) << 16);
}
__device__ __forceinline__ void gload16(const ushort* g, ushort* l) {
    __builtin_amdgcn_global_load_lds((const __attribute__((address_space(1))) void*)g,
                                     (__attribute__((address_space(3))) void*)l, 16, 0, 0);
}

// ---------------------------------------------------------------------------
// bf16 MFMA GEMM, double-buffered prefetch K-loop.
// C[M,N] = act( A[M,K]bf16 @ Wt[N,K]bf16^T + bias1[n] + bias2[n]*srow[m] )
// Tile 128x128, 4 waves (each 64x64), BK=32, 16x16x32 mfma.
// ---------------------------------------------------------------------------
__global__ __launch_bounds__(256, 3) void mgemm(
    const ushort* __restrict__ A, int lda,
    const ushort* __restrict__ Wt,
    const float* __restrict__ bias1,
    const float* __restrict__ bias2,
    const float* __restrict__ srow,
    float* outF, ushort* outB, int ldo,
    int K, int act)
{
    __shared__ ushort sA[2][128 * 32];
    __shared__ ushort sB[2][128 * 32];
    const int wv = threadIdx.x >> 6, lane = threadIdx.x & 63;
    const int rh = wv & 1, ch = wv >> 1;
    const int m0 = blockIdx.y * 128, n0 = blockIdx.x * 128;

    f32x4 acc[4][4];
#pragma unroll
    for (int i = 0; i < 4; i++)
#pragma unroll
        for (int j = 0; j < 4; j++) acc[i][j] = (f32x4){0.f, 0.f, 0.f, 0.f};

    const ushort* Ab = A + (size_t)m0 * lda;
    const ushort* Wb = Wt + (size_t)n0 * K;

    auto stage = [&](int b, int k0) {
#pragma unroll
        for (int i = 0; i < 2; i++) {
            int c = wv * 2 + i;
            int u = c * 64 + lane;
            int row = u >> 2, p = u & 3;
            int q = (p - (row >> 1)) & 3;
            gload16(Ab + (size_t)row * lda + k0 + q * 8, sA[b] + c * 512);
            gload16(Wb + (size_t)row * K + k0 + q * 8, sB[b] + c * 512);
        }
    };

    const int nsteps = K >> 5;
    stage(0, 0);
    int buf = 0;
    for (int s = 0; s < nsteps; s++) {
        __syncthreads();                       // prefetch for buf complete
        if (s + 1 < nsteps) stage(buf ^ 1, (s + 1) << 5);
        const int qg = lane >> 4;
        bf16x8 af[4], bfr[4];
#pragma unroll
        for (int bi = 0; bi < 4; bi++) {
            int r = rh * 64 + bi * 16 + (lane & 15);
            af[bi] = *(const bf16x8*)(sA[buf] + (r * 4 + ((qg + (r >> 1)) & 3)) * 8);
        }
#pragma unroll
        for (int bj = 0; bj < 4; bj++) {
            int r = ch * 64 + bj * 16 + (lane & 15);
            bfr[bj] = *(const bf16x8*)(sB[buf] + (r * 4 + ((qg + (r >> 1)) & 3)) * 8);
        }
#pragma unroll
        for (int bi = 0; bi < 4; bi++)
#pragma unroll
            for (int bj = 0; bj < 4; bj++)
                acc[bi][bj] = __builtin_amdgcn_mfma_f32_16x16x32_bf16(
                    af[bi], bfr[bj], acc[bi][bj], 0, 0, 0);
        buf ^= 1;
    }

#pragma unroll
    for (int bi = 0; bi < 4; bi++) {
#pragma unroll
        for (int r = 0; r < 4; r++) {
            int m = m0 + rh * 64 + bi * 16 + (lane >> 4) * 4 + r;
            float sv = srow ? srow[m] : 1.0f;
#pragma unroll
            for (int bj = 0; bj < 4; bj++) {
                int n = n0 + ch * 64 + bj * 16 + (lane & 15);
                float v = acc[bi][bj][r];
                if (bias1) v += bias1[n];
                if (bias2) v += bias2[n] * sv;
                if (act) v = gelu_f(v);
                if (outF) outF[(size_t)m * ldo + n] = v;
                if (outB) outB[(size_t)m * ldo + n] = f2b(v);
            }
        }
    }
}

// ---------------------------------------------------------------------------
// weight transpose+convert: out[n*ldo + k] = bf16(src[rowmap(k)*N + n])
// ---------------------------------------------------------------------------
#define NJOBS 16
struct TJobsArg {
    const float* src[NJOBS];
    long dst[NJOBS];
    int K[NJOBS], N[NJOBS], split[NJOBS], off0[NJOBS], off1[NJOBS], ldo[NJOBS];
};

__global__ __launch_bounds__(256) void tw_kernel(TJobsArg ja, ushort* wbuf)
{
    int j = blockIdx.y;
    int K = ja.K[j], N = ja.N[j];
    int tk = K >> 5, tn = N >> 5;
    int t = blockIdx.x;
    if (t >= tk * tn) return;
    int kt = t % tk, nt = t / tk;
    const float* src = ja.src[j];
    ushort* out = wbuf + ja.dst[j];
    int ldo = ja.ldo[j];
    __shared__ float L[32][33];
    int r = threadIdx.x >> 5, c = threadIdx.x & 31;
#pragma unroll
    for (int rr = 0; rr < 4; rr++) {
        int k = kt * 32 + rr * 8 + r;
        int srow = (k < ja.split[j]) ? ja.off0[j] + k : ja.off1[j] + k - ja.split[j];
        L[rr * 8 + r][c] = src[(size_t)srow * N + nt * 32 + c];
    }
    __syncthreads();
#pragma unroll
    for (int rr = 0; rr < 4; rr++) {
        int n = nt * 32 + rr * 8 + r;
        out[(size_t)n * ldo + kt * 32 + c] = f2b(L[c][rr * 8 + r]);
    }
}

// fp32 -> bf16 bulk convert (count % 4 == 0)
__global__ void f2b_kernel(const float* __restrict__ s, ushort* __restrict__ d, int n4)
{
    int i = blockIdx.x * blockDim.x + threadIdx.x;
    if (i >= n4) return;
    float4 v = ((const float4*)s)[i];
    ushort4 o;
    o.x = f2b(v.x); o.y = f2b(v.y); o.z = f2b(v.z); o.w = f2b(v.w);
    ((ushort4*)d)[i] = o;
}

// ---------------------------------------------------------------------------
// Graph-per-block edge kernel. PB row n: [Pd(O)|Ps(O)|Ad(O)|As(O)|skip(O)].
// Vectorized LDS reads (b128), fast gelu, att2_w cached in LDS.
// cshift = log2(O/8).
// ---------------------------------------------------------------------------
__global__ __launch_bounds__(256) void edge_kernel(
    const ushort* __restrict__ PB, const float* __restrict__ att2_w,
    ushort* __restrict__ Gout, int ldG, float* __restrict__ S, int O, int cshift)
{
    __shared__ ushort sPB[9 * 2048];
    __shared__ float sAw[512];
    __shared__ float logits[72];
    __shared__ float aw[72];
    const int g = blockIdx.x;
    const int tid = threadIdx.x, lane = tid & 63, wave = tid >> 6;
    const int O4 = O * 4, O5 = O * 5;
    const int cpr = O >> 7;             // 1KB chunks per 4O-row
    const int total = 9 * cpr;
    const ushort* gbase = PB + (size_t)g * 9 * O5;

    for (int i = wave; i < total; i += 4) {
        int row = i / cpr, co = i - row * cpr;
        gload16(gbase + (size_t)row * O5 + co * 512 + lane * 8, sPB + i * 512);
    }
    for (int c = tid; c < O; c += 256) sAw[c] = att2_w[c];
    __syncthreads();

    for (int e = wave; e < 72; e += 4) {
        int d = e >> 3, k = e & 7;
        int s = k + (k >= d);
        const ushort* ad = sPB + d * O4 + 2 * O;
        const ushort* as = sPB + s * O4 + 3 * O;
        float p = 0.f;
        for (int c0 = lane * 4; c0 < O; c0 += 256) {
            ushort4 a4 = *(const ushort4*)(ad + c0);
            ushort4 s4 = *(const ushort4*)(as + c0);
            const ushort* ap = (const ushort*)&a4;
            const ushort* sp = (const ushort*)&s4;
#pragma unroll
            for (int j = 0; j < 4; j++) {
                float v = b2f(ap[j]) + b2f(sp[j]);
                v = v > 0.f ? v : 0.01f * v;
                p += v * sAw[c0 + j];
            }
        }
#pragma unroll
        for (int off = 32; off; off >>= 1) p += __shfl_down(p, off, 64);
        if (lane == 0) logits[e] = p;     // att2_b cancels in softmax
    }
    __syncthreads();

    if (tid < 9) {
        float m = -INFINITY;
#pragma unroll
        for (int k = 0; k < 8; k++) m = fmaxf(m, logits[tid * 8 + k]);
        float s = 0.f, ee[8];
#pragma unroll
        for (int k = 0; k < 8; k++) { ee[k] = expf(logits[tid * 8 + k] - m); s += ee[k]; }
        float inv = 1.0f / (s + 1e-16f);
#pragma unroll
        for (int k = 0; k < 8; k++) aw[tid * 8 + k] = ee[k] * inv;
        S[g * 9 + tid] = s * inv;
    }
    __syncthreads();

    const int nch = O >> 3;
    for (int idx = tid; idx < 9 * nch; idx += 256) {
        int n = idx >> cshift, cc = idx & (nch - 1);
        bf16x8 pdv = *(const bf16x8*)(sPB + n * O4 + cc * 8);
        const ushort* pp = (const ushort*)&pdv;
        float acc8[8];
#pragma unroll
        for (int j = 0; j < 8; j++) acc8[j] = 0.f;
#pragma unroll
        for (int k = 0; k < 8; k++) {
            int s = k + (k >= n);
            float w = aw[n * 8 + k];
            bf16x8 psv = *(const bf16x8*)(sPB + s * O4 + O + cc * 8);
            const ushort* qp = (const ushort*)&psv;
#pragma unroll
            for (int j = 0; j < 8; j++)
                acc8[j] += w * gelu_fast(b2f(pp[j]) + b2f(qp[j]));
        }
        ushort o8[8];
#pragma unroll
        for (int j = 0; j < 8; j++) o8[j] = f2b(acc8[j]);
        *(bf16x8*)(Gout + (size_t)(g * 9 + n) * ldG + cc * 8) = *(const bf16x8*)o8;
    }
}

// ---------------------------------------------------------------------------
// LayerNorm of h = UD + skip_pre(bf16, PB col 4O, stride ld5).
// Register-cached (O <= 512). Batched remap for rows >= rowsplit.
// ---------------------------------------------------------------------------
__global__ __launch_bounds__(256) void ln_kernel(
    const float* __restrict__ UD, const ushort* __restrict__ PBs, int ld5,
    const float* __restrict__ gw, const float* __restrict__ bw,
    ushort* outB, int ldoB, int rowsplit, float* outF, int O)
{
    __shared__ float sm[4];
    const int n = blockIdx.x, tid = threadIdx.x;
    const int lane = tid & 63, wid = tid >> 6;
    const float* ur = UD + (size_t)n * O;
    const ushort* sr = PBs + (size_t)n * ld5;
    const int cnt = O >> 8;     // 1 or 2

    float vals[2];
    float sum = 0.f;
#pragma unroll
    for (int i = 0; i < 2; i++) {
        if (i < cnt) {
            int c = tid + 256 * i;
            vals[i] = ur[c] + b2f(sr[c]);
            sum += vals[i];
        }
    }
#pragma unroll
    for (int off = 32; off; off >>= 1) sum += __shfl_down(sum, off, 64);
    if (lane == 0) sm[wid] = sum;
    __syncthreads();
    const float mu = (sm[0] + sm[1] + sm[2] + sm[3]) / (float)O;
    __syncthreads();

    float var = 0.f;
#pragma unroll
    for (int i = 0; i < 2; i++) {
        if (i < cnt) { float d = vals[i] - mu; var += d * d; }
    }
#pragma unroll
    for (int off = 32; off; off >>= 1) var += __shfl_down(var, off, 64);
    if (lane == 0) sm[wid] = var;
    __syncthreads();
    const float rstd = rsqrtf((sm[0] + sm[1] + sm[2] + sm[3]) / (float)O + 1e-5f);

    int orow = n, coloff = 0;
    if (n >= rowsplit) { orow = n - rowsplit; coloff = 256; }
#pragma unroll
    for (int i = 0; i < 2; i++) {
        if (i < cnt) {
            int c = tid + 256 * i;
            float v = (vals[i] - mu) * rstd * gw[c] + bw[c];
            if (outB) outB[(size_t)orow * ldoB + coloff + c] = f2b(v);
            if (outF) outF[(size_t)n * O + c] = v;   // may alias UD
        }
    }
}

// ---------------------------------------------------------------------------
// prep: concat biases, pos fills (ixa1 batched 18432 rows), vb, pw2 bf16
// ---------------------------------------------------------------------------
__global__ void prep_kernel(
    const float* __restrict__ pw1_b1, const float* __restrict__ att1_b1, const float* __restrict__ skip_b1,
    const float* __restrict__ pw1_b2, const float* __restrict__ att1_b2, const float* __restrict__ skip_b2,
    const float* __restrict__ pos_table,
    const float* __restrict__ pw2_b1, const float* __restrict__ upd_w1,
    const float* __restrict__ pw2_b2, const float* __restrict__ upd_w2,
    const float* __restrict__ pw2_w1, const float* __restrict__ pw2_w2,
    float* biasC1, float* biasC2, ushort* ixa1, ushort* ixa2,
    float* vb1, float* vb2, ushort* pw2f1, ushort* pw2f2)
{
    int i = blockIdx.x * 256 + threadIdx.x;
    if (i < 1280) {
        float v;
        if (i < 256) v = pw1_b1[i];
        else if (i < 512) v = 0.f;
        else if (i < 768) v = att1_b1[i - 512];
        else if (i < 1024) v = 0.f;
        else v = skip_b1[i - 1024];
        biasC1[i] = v;
        return;
    }
    i -= 1280;
    if (i < 2560) {
        float v;
        if (i < 512) v = pw1_b2[i];
        else if (i < 1024) v = 0.f;
        else if (i < 1536) v = att1_b2[i - 1024];
        else if (i < 2048) v = 0.f;
        else v = skip_b2[i - 2048];
        biasC2[i] = v;
        return;
    }
    i -= 2560;
    if (i < NN2 * POSD) {
        int n = i >> 6, c = i & 63;
        ixa1[(size_t)n * 576 + 256 + c] = f2b(pos_table[(n % NPG) * POSD + c]);
        return;
    }
    i -= NN2 * POSD;
    if (i < NN * POSD) {
        int n = i >> 6, c = i & 63;
        ixa2[(size_t)n * 1088 + 512 + c] = f2b(pos_table[(n % NPG) * POSD + c]);
        return;
    }
    i -= NN * POSD;
    if (i < 256) {
        float a = 0.f;
        for (int j = 0; j < 256; j++) a += pw2_b1[j] * upd_w1[(size_t)(320 + j) * 256 + i];
        vb1[i] = a;
        return;
    }
    i -= 256;
    if (i < 512) {
        float a = 0.f;
        for (int j = 0; j < 512; j++) a += pw2_b2[j] * upd_w2[(size_t)(576 + j) * 512 + i];
        vb2[i] = a;
        return;
    }
    i -= 512;
    if (i < 256 * 256) { pw2f1[i] = f2b(pw2_w1[i]); return; }
    i -= 256 * 256;
    if (i < 512 * 512) { pw2f2[i] = f2b(pw2_w2[i]); return; }
}

// ---------------------------------------------------------------------------
// head: pool(9 rows) + cls1 (gelu) + cls2, 4 graphs per block
// ---------------------------------------------------------------------------
__global__ __launch_bounds__(256) void head_kernel(
    const float* __restrict__ h2,
    const float* __restrict__ cls1_w, const float* __restrict__ cls1_b,
    const float* __restrict__ cls2_w, const float* __restrict__ cls2_b,
    float* __restrict__ out)
{
    __shared__ float pooled[4][512];
    __shared__ float hid[4][256];
    const int b = blockIdx.x, tid = threadIdx.x;

    for (int idx = tid; idx < 4 * 512; idx += 256) {
        int gi = idx >> 9, c = idx & 511;
        const float* base = h2 + (size_t)((b * 4 + gi) * 9) * 512 + c;
        float s = 0.f;
#pragma unroll
        for (int k = 0; k < NPG; k++) s += base[(size_t)k * 512];
        pooled[gi][c] = s;
    }
    __syncthreads();

    {
        float acc[4] = {0.f, 0.f, 0.f, 0.f};
        for (int c = 0; c < 512; c++) {
            float w = cls1_w[(size_t)c * 256 + tid];
#pragma unroll
            for (int gi = 0; gi < 4; gi++) acc[gi] += pooled[gi][c] * w;
        }
        float bb = cls1_b[tid];
#pragma unroll
        for (int gi = 0; gi < 4; gi++) hid[gi][tid] = gelu_f(acc[gi] + bb);
    }
    __syncthreads();

    {
        int gi = tid >> 6, lane = tid & 63;
        float p = 0.f;
#pragma unroll
        for (int i = 0; i < 4; i++) p += hid[gi][lane + 64 * i] * cls2_w[lane + 64 * i];
#pragma unroll
        for (int off = 32; off; off >>= 1) p += __shfl_down(p, off, 64);
        if (lane == 0) out[b * 4 + gi] = p + cls2_b[0];
    }
}

// ---------------------------------------------------------------------------
// Host side
// ---------------------------------------------------------------------------
static inline void mg(hipStream_t st, int M, int N, int K,
                      const ushort* A, int lda, const ushort* Wt,
                      const float* bias1, const float* bias2, const float* srow,
                      float* outF, ushort* outB, int ldo, int act)
{
    dim3 grid(N / 128, M / 128);
    mgemm<<<grid, dim3(256), 0, st>>>(A, lda, Wt, bias1, bias2, srow, outF, outB, ldo, K, act);
}

extern "C" void kernel_launch(void* const* d_in, const int* in_sizes, int n_in,
                              void* d_out, int out_size, void* d_ws, size_t ws_size,
                              hipStream_t stream)
{
    (void)in_sizes; (void)n_in; (void)out_size; (void)ws_size;
    const float* feat_low   = (const float*)d_in[0];
    const float* feat_high  = (const float*)d_in[1];
    const float* pos_table  = (const float*)d_in[4];
    const float* proj_low_b  = (const float*)d_in[6];
    const float* proj_high_b = (const float*)d_in[8];
    const float* cls1_w = (const float*)d_in[37];
    const float* cls1_b = (const float*)d_in[38];
    const float* cls2_w = (const float*)d_in[39];
    const float* cls2_b = (const float*)d_in[40];
    float* out = (float*)d_out;

    const float* att2_w1 = (const float*)d_in[15];
    const float* upd_b1  = (const float*)d_in[18];
    const float* ln_g1   = (const float*)d_in[19];
    const float* ln_b1   = (const float*)d_in[20];
    const float* att2_w2 = (const float*)d_in[29];
    const float* upd_b2  = (const float*)d_in[32];
    const float* ln_g2   = (const float*)d_in[33];
    const float* ln_b2   = (const float*)d_in[34];

    // ---- workspace layout (256B aligned) ----
    char* base = (char*)d_ws;
    size_t cur = 0;
    auto alloc = [&](size_t bytes) { void* p = base + cur; cur += (bytes + 255) & ~(size_t)255; return p; };
    void*   PBreg = alloc((size_t)NN2 * 1280 * 2);  // PB; featB alias (disjoint in time)
    ushort* PB    = (ushort*)PBreg;
    ushort* featB = (ushort*)PBreg;
    ushort* ixa1  = (ushort*)alloc((size_t)NN2 * 576 * 2);
    ushort* ixa2  = (ushort*)alloc((size_t)NN * 1088 * 2);
    float*  UD    = (float*)alloc((size_t)NN2 * 256 * 4); // == NN*512*4 for stage2
    float*  S     = (float*)alloc((size_t)NN2 * 4);
    float*  biasC1 = (float*)alloc(1280 * 4);
    float*  biasC2 = (float*)alloc(2560 * 4);
    float*  vb1   = (float*)alloc(256 * 4);
    float*  vb2   = (float*)alloc(512 * 4);
    ushort* wbuf  = (ushort*)alloc((size_t)3700000 * 2);

    // ---- weight transpose jobs ----
    TJobsArg ja;
    long woff[18];
    {
        const float* s1_pw1 = (const float*)d_in[9];
        const float* s1_att = (const float*)d_in[13];
        const float* s1_upd = (const float*)d_in[17];
        const float* s1_skp = (const float*)d_in[21];
        const float* s2_pw1 = (const float*)d_in[23];
        const float* s2_att = (const float*)d_in[27];
        const float* s2_upd = (const float*)d_in[31];
        const float* s2_skp = (const float*)d_in[35];
        const float* proj_low_w  = (const float*)d_in[5];
        const float* proj_high_w = (const float*)d_in[7];
        struct J { const float* s; int K, N, split, o0, o1, ldo; long sz; };
        J js[NJOBS] = {
            {proj_low_w,  512, 256, 512, 0, 0, 512, 512L * 256},     // 0
            {proj_high_w, 1024, 256, 1024, 0, 0, 1024, 1024L * 256}, // 1
            {s1_pw1, 320, 256, 320, 0, 0, 320, 320L * 256},          // 2 big5-1
            {s1_pw1, 320, 256, 320, 320, 0, 320, 320L * 256},        // 3
            {s1_att, 320, 256, 256, 0, 512, 320, 320L * 256},        // 4
            {s1_att, 320, 256, 256, 256, 576, 320, 320L * 256},      // 5
            {s1_skp, 320, 256, 320, 0, 0, 320, 320L * 256},          // 6
            {s1_upd, 320, 256, 320, 0, 0, 576, 576L * 256},          // 7 updW1
            {s1_upd, 256, 256, 256, 320, 0, 256, 256L * 256},        // 8 updbT1
            {s2_pw1, 576, 512, 576, 0, 0, 576, 576L * 512},          // 9 big5-2
            {s2_pw1, 576, 512, 576, 576, 0, 576, 576L * 512},        // 10
            {s2_att, 576, 512, 512, 0, 1024, 576, 576L * 512},       // 11
            {s2_att, 576, 512, 512, 512, 1088, 576, 576L * 512},     // 12
            {s2_skp, 576, 512, 576, 0, 0, 576, 576L * 512},          // 13
            {s2_upd, 576, 512, 576, 0, 0, 1088, 1088L * 512},        // 14 updW2
            {s2_upd, 512, 512, 512, 576, 0, 512, 512L * 512},        // 15 updbT2
        };
        long off = 0;
        for (int i = 0; i < NJOBS; i++) {
            ja.src[i] = js[i].s; ja.K[i] = js[i].K; ja.N[i] = js[i].N;
            ja.split[i] = js[i].split; ja.off0[i] = js[i].o0; ja.off1[i] = js[i].o1;
            ja.ldo[i] = js[i].ldo;
            ja.dst[i] = off; woff[i] = off;
            off += js[i].sz;
        }
        woff[16] = off; off += 256L * 256;   // pw2f1
        woff[17] = off;                       // pw2f2
    }
    tw_kernel<<<dim3(288, NJOBS), dim3(256), 0, stream>>>(ja, wbuf);

    ushort* updW1  = wbuf + woff[7];
    ushort* updbT1 = wbuf + woff[8];
    ushort* updW2  = wbuf + woff[14];
    ushort* updbT2 = wbuf + woff[15];
    ushort* pw2f1  = wbuf + woff[16];
    ushort* pw2f2  = wbuf + woff[17];

    // ---- prep ----
    {
        int tot = 1280 + 2560 + NN2 * POSD + NN * POSD + 256 + 512 + 256 * 256 + 512 * 512;
        prep_kernel<<<dim3((tot + 255) / 256), dim3(256), 0, stream>>>(
            (const float*)d_in[10], (const float*)d_in[14], (const float*)d_in[22],
            (const float*)d_in[24], (const float*)d_in[28], (const float*)d_in[36],
            pos_table,
            (const float*)d_in[12], (const float*)d_in[17],
            (const float*)d_in[26], (const float*)d_in[31],
            (const float*)d_in[11], (const float*)d_in[25],
            biasC1, biasC2, ixa1, ixa2, vb1, vb2, pw2f1, pw2f2);
    }

    // ---- Wcomb = pw2 @ updb, transposed into updW cols [I, I+O) ----
    mg(stream, 256, 256, 256, updbT1, 256, pw2f1, 0, 0, 0, 0, updW1 + 320, 576, 0);
    mg(stream, 512, 512, 512, updbT2, 512, pw2f2, 0, 0, 0, 0, updW2 + 576, 1088, 0);

    // ---- stage 1 (batched low|high, M = 18432) ----
    f2b_kernel<<<dim3(NN * 512 / 4 / 256), dim3(256), 0, stream>>>(feat_low, featB, NN * 512 / 4);
    f2b_kernel<<<dim3(NN * 1024 / 4 / 256), dim3(256), 0, stream>>>(
        feat_high, featB + (size_t)NN * 512, NN * 1024 / 4);
    mg(stream, NN, 256, 512, featB, 512, wbuf + woff[0], proj_low_b, 0, 0, 0, ixa1, 576, 0);
    mg(stream, NN, 256, 1024, featB + (size_t)NN * 512, 1024, wbuf + woff[1], proj_high_b, 0, 0,
       0, ixa1 + (size_t)NN * 576, 576, 0);

    mg(stream, NN2, 1280, 320, ixa1, 576, wbuf + woff[2], biasC1, 0, 0, 0, PB, 1280, 0);
    edge_kernel<<<dim3(2 * NUM_GRAPHS), dim3(256), 0, stream>>>(
        PB, att2_w1, ixa1 + 320, 576, S, 256, 5);
    mg(stream, NN2, 256, 576, ixa1, 576, updW1, upd_b1, vb1, S, UD, 0, 256, 1);
    ln_kernel<<<dim3(NN2), dim3(256), 0, stream>>>(UD, PB + 4 * 256, 1280,
                                                   ln_g1, ln_b1, ixa2, 1088, NN, 0, 256);

    // ---- stage 2 ----
    mg(stream, NN, 2560, 576, ixa2, 1088, wbuf + woff[9], biasC2, 0, 0, 0, PB, 2560, 0);
    edge_kernel<<<dim3(NUM_GRAPHS), dim3(256), 0, stream>>>(
        PB, att2_w2, ixa2 + 576, 1088, S, 512, 6);
    mg(stream, NN, 512, 1088, ixa2, 1088, updW2, upd_b2, vb2, S, UD, 0, 512, 1);
    ln_kernel<<<dim3(NN), dim3(256), 0, stream>>>(UD, PB + 4 * 512, 2560,
                                                  ln_g2, ln_b2, 0, 0, 1 << 30, UD, 512);

    // ---- head ----
    head_kernel<<<dim3(NUM_GRAPHS / 4), dim3(256), 0, stream>>>(UD, cls1_w, cls1_b, cls2_w, cls2_b, out);
}

// Round 7
// 607.087 us; speedup vs baseline: 3.6908x; 1.1080x over previous
//
#include <hip/hip_runtime.h>
#include <math.h>

// ---------- model constants ----------
#define NUM_GRAPHS 1024
#define NPG 9
#define NN 9216            // nodes
#define NN2 18432          // batched stage-1 rows (low|high)
#define POSD 64

typedef __attribute__((ext_vector_type(8))) short bf16x8;
typedef __attribute__((ext_vector_type(4))) float f32x4;

__device__ __forceinline__ float gelu_f(float x) {
    return 0.5f * x * (1.0f + erff(x * 0.70710678118654752f));
}
// fast gelu (tanh form), |err| <= ~3e-3 vs erf-gelu (edge aggregation only)
__device__ __forceinline__ float gelu_fast(float x) {
    float y = 0.7978845608f * x * (1.0f + 0.044715f * x * x);
    float t = __expf(-2.0f * fabsf(y));
    float r = (1.0f - t) / (1.0f + t);
    r = copysignf(r, y);
    return 0.5f * x * (1.0f + r);
}
__device__ __forceinline__ ushort f2b(float v) {
    unsigned u = __float_as_uint(v);
    return (ushort)((u + 0x7fffu + ((u >> 16) & 1u)) >> 16);
}
__device__ __forceinline__ float b2f(ushort u) {
    return __uint_as_float(((unsigned)u) << 16);
}
__device__ __forceinline__ void gload16(const ushort* g, ushort* l) {
    __builtin_amdgcn_global_load_lds((const __attribute__((address_space(1))) void*)g,
                                     (__attribute__((address_space(3))) void*)l, 16, 0, 0);
}

// ---------------------------------------------------------------------------
// bf16 MFMA GEMM, double-buffered, optional split-K via blockIdx.z.
// C[M,N] = A[M,K@z]bf16 @ Wt[N,K@z]^T + bias1[n] + prow[(m%9)*ldp + n]
// Tile 128x128, 4 waves, BK=32. outF gets per-chunk partials (+z*partStride).
// ---------------------------------------------------------------------------
__global__ __launch_bounds__(256, 4) void mgemm(
    const ushort* __restrict__ A, int lda,
    const ushort* __restrict__ Wt, int ldw,
    const float* __restrict__ bias1,
    const float* __restrict__ prow, int ldp,
    float* outF, ushort* outB, int ldo,
    long partStride, int K)
{
    __shared__ ushort sA[2][128 * 32];
    __shared__ ushort sB[2][128 * 32];
    const int wv = threadIdx.x >> 6, lane = threadIdx.x & 63;
    const int rh = wv & 1, ch = wv >> 1;
    const int m0 = blockIdx.y * 128, n0 = blockIdx.x * 128;
    const int koff = blockIdx.z * K;

    f32x4 acc[4][4];
#pragma unroll
    for (int i = 0; i < 4; i++)
#pragma unroll
        for (int j = 0; j < 4; j++) acc[i][j] = (f32x4){0.f, 0.f, 0.f, 0.f};

    const ushort* Ab = A + (size_t)m0 * lda + koff;
    const ushort* Wb = Wt + (size_t)n0 * ldw + koff;
    if (outF) outF += (size_t)blockIdx.z * partStride;

    auto stage = [&](int b, int k0) {
#pragma unroll
        for (int i = 0; i < 2; i++) {
            int c = wv * 2 + i;
            int u = c * 64 + lane;
            int row = u >> 2, p = u & 3;
            int q = (p - (row >> 1)) & 3;
            gload16(Ab + (size_t)row * lda + k0 + q * 8, sA[b] + c * 512);
            gload16(Wb + (size_t)row * ldw + k0 + q * 8, sB[b] + c * 512);
        }
    };

    const int nsteps = K >> 5;
    stage(0, 0);
    int buf = 0;
    for (int s = 0; s < nsteps; s++) {
        __syncthreads();                       // prefetch for buf complete
        if (s + 1 < nsteps) stage(buf ^ 1, (s + 1) << 5);
        const int qg = lane >> 4;
        bf16x8 af[4], bfr[4];
#pragma unroll
        for (int bi = 0; bi < 4; bi++) {
            int r = rh * 64 + bi * 16 + (lane & 15);
            af[bi] = *(const bf16x8*)(sA[buf] + (r * 4 + ((qg + (r >> 1)) & 3)) * 8);
        }
#pragma unroll
        for (int bj = 0; bj < 4; bj++) {
            int r = ch * 64 + bj * 16 + (lane & 15);
            bfr[bj] = *(const bf16x8*)(sB[buf] + (r * 4 + ((qg + (r >> 1)) & 3)) * 8);
        }
#pragma unroll
        for (int bi = 0; bi < 4; bi++)
#pragma unroll
            for (int bj = 0; bj < 4; bj++)
                acc[bi][bj] = __builtin_amdgcn_mfma_f32_16x16x32_bf16(
                    af[bi], bfr[bj], acc[bi][bj], 0, 0, 0);
        buf ^= 1;
    }

#pragma unroll
    for (int bi = 0; bi < 4; bi++) {
#pragma unroll
        for (int r = 0; r < 4; r++) {
            int m = m0 + rh * 64 + bi * 16 + (lane >> 4) * 4 + r;
            int r9 = m % 9;
#pragma unroll
            for (int bj = 0; bj < 4; bj++) {
                int n = n0 + ch * 64 + bj * 16 + (lane & 15);
                float v = acc[bi][bj][r];
                if (bias1) v += bias1[n];
                if (prow) v += prow[r9 * ldp + n];
                if (outF) outF[(size_t)m * ldo + n] = v;
                if (outB) outB[(size_t)m * ldo + n] = f2b(v);
            }
        }
    }
}

// ---------------------------------------------------------------------------
// weight transpose+convert: out[n*ldo + k] = bf16(src[(off0+k)*N + n])
// ---------------------------------------------------------------------------
#define NJOBS 16
struct TJobsArg {
    const float* src[NJOBS];
    long dst[NJOBS];
    int K[NJOBS], N[NJOBS], off0[NJOBS], ldo[NJOBS];
};

__global__ __launch_bounds__(256) void tw_kernel(TJobsArg ja, ushort* wbuf)
{
    int j = blockIdx.y;
    int K = ja.K[j], N = ja.N[j];
    int tk = K >> 5, tn = N >> 5;
    int t = blockIdx.x;
    if (t >= tk * tn) return;
    int kt = t % tk, nt = t / tk;
    const float* src = ja.src[j];
    ushort* out = wbuf + ja.dst[j];
    int ldo = ja.ldo[j];
    __shared__ float L[32][33];
    int r = threadIdx.x >> 5, c = threadIdx.x & 31;
#pragma unroll
    for (int rr = 0; rr < 4; rr++) {
        int k = kt * 32 + rr * 8 + r;
        L[rr * 8 + r][c] = src[(size_t)(ja.off0[j] + k) * N + nt * 32 + c];
    }
    __syncthreads();
#pragma unroll
    for (int rr = 0; rr < 4; rr++) {
        int n = nt * 32 + rr * 8 + r;
        out[(size_t)n * ldo + kt * 32 + c] = f2b(L[c][rr * 8 + r]);
    }
}

// fp32 -> bf16 bulk convert (count % 4 == 0)
__global__ void f2b_kernel(const float* __restrict__ s, ushort* __restrict__ d, int n4)
{
    int i = blockIdx.x * blockDim.x + threadIdx.x;
    if (i >= n4) return;
    float4 v = ((const float4*)s)[i];
    ushort4 o;
    o.x = f2b(v.x); o.y = f2b(v.y); o.z = f2b(v.z); o.w = f2b(v.w);
    ((ushort4*)d)[i] = o;
}

// proj partial reduce: ixa1[n][0..256) = bf16(P0+P1+bias), low rows then high
__global__ void pjred_kernel(const float* __restrict__ PT,
                             const float* __restrict__ bl, const float* __restrict__ bh,
                             ushort* __restrict__ ixa1)
{
    int i = blockIdx.x * 256 + threadIdx.x;
    if (i >= NN2 * 64) return;
    int n = i >> 6, cq = i & 63;
    const float *p0, *p1, *bb; int r;
    if (n < NN) { p0 = PT; p1 = PT + (size_t)NN * 256; bb = bl; r = n; }
    else { p0 = PT + (size_t)2 * NN * 256; p1 = PT + (size_t)3 * NN * 256; bb = bh; r = n - NN; }
    float4 a = ((const float4*)(p0 + (size_t)r * 256))[cq];
    float4 b = ((const float4*)(p1 + (size_t)r * 256))[cq];
    float4 bs = ((const float4*)bb)[cq];
    ushort4 o;
    o.x = f2b(a.x + b.x + bs.x); o.y = f2b(a.y + b.y + bs.y);
    o.z = f2b(a.z + b.z + bs.z); o.w = f2b(a.w + b.w + bs.w);
    ((ushort4*)(ixa1 + (size_t)n * 512))[cq] = o;
}

// ---------------------------------------------------------------------------
// Graph-per-block edge kernel. PB row n: [Pd(O)|Ps(O)|Ad(O)|As(O)|skip(O)].
// ---------------------------------------------------------------------------
__global__ __launch_bounds__(256) void edge_kernel(
    const ushort* __restrict__ PB, const float* __restrict__ att2_w,
    ushort* __restrict__ Gout, int ldG, float* __restrict__ S, int O, int cshift)
{
    __shared__ ushort sPB[9 * 2048];
    __shared__ float sAw[512];
    __shared__ float logits[72];
    __shared__ float aw[72];
    const int g = blockIdx.x;
    const int tid = threadIdx.x, lane = tid & 63, wave = tid >> 6;
    const int O4 = O * 4, O5 = O * 5;
    const int cpr = O >> 7;
    const int total = 9 * cpr;
    const ushort* gbase = PB + (size_t)g * 9 * O5;

    for (int i = wave; i < total; i += 4) {
        int row = i / cpr, co = i - row * cpr;
        gload16(gbase + (size_t)row * O5 + co * 512 + lane * 8, sPB + i * 512);
    }
    for (int c = tid; c < O; c += 256) sAw[c] = att2_w[c];
    __syncthreads();

    for (int e = wave; e < 72; e += 4) {
        int d = e >> 3, k = e & 7;
        int s = k + (k >= d);
        const ushort* ad = sPB + d * O4 + 2 * O;
        const ushort* as = sPB + s * O4 + 3 * O;
        float p = 0.f;
        for (int c0 = lane * 4; c0 < O; c0 += 256) {
            ushort4 a4 = *(const ushort4*)(ad + c0);
            ushort4 s4 = *(const ushort4*)(as + c0);
            const ushort* ap = (const ushort*)&a4;
            const ushort* sp = (const ushort*)&s4;
#pragma unroll
            for (int j = 0; j < 4; j++) {
                float v = b2f(ap[j]) + b2f(sp[j]);
                v = v > 0.f ? v : 0.01f * v;
                p += v * sAw[c0 + j];
            }
        }
#pragma unroll
        for (int off = 32; off; off >>= 1) p += __shfl_down(p, off, 64);
        if (lane == 0) logits[e] = p;     // att2_b cancels in softmax
    }
    __syncthreads();

    if (tid < 9) {
        float m = -INFINITY;
#pragma unroll
        for (int k = 0; k < 8; k++) m = fmaxf(m, logits[tid * 8 + k]);
        float s = 0.f, ee[8];
#pragma unroll
        for (int k = 0; k < 8; k++) { ee[k] = expf(logits[tid * 8 + k] - m); s += ee[k]; }
        float inv = 1.0f / (s + 1e-16f);
#pragma unroll
        for (int k = 0; k < 8; k++) aw[tid * 8 + k] = ee[k] * inv;
        S[g * 9 + tid] = s * inv;
    }
    __syncthreads();

    const int nch = O >> 3;
    for (int idx = tid; idx < 9 * nch; idx += 256) {
        int n = idx >> cshift, cc = idx & (nch - 1);
        bf16x8 pdv = *(const bf16x8*)(sPB + n * O4 + cc * 8);
        const ushort* pp = (const ushort*)&pdv;
        float acc8[8];
#pragma unroll
        for (int j = 0; j < 8; j++) acc8[j] = 0.f;
#pragma unroll
        for (int k = 0; k < 8; k++) {
            int s = k + (k >= n);
            float w = aw[n * 8 + k];
            bf16x8 psv = *(const bf16x8*)(sPB + s * O4 + O + cc * 8);
            const ushort* qp = (const ushort*)&psv;
#pragma unroll
            for (int j = 0; j < 8; j++)
                acc8[j] += w * gelu_fast(b2f(pp[j]) + b2f(qp[j]));
        }
        ushort o8[8];
#pragma unroll
        for (int j = 0; j < 8; j++) o8[j] = f2b(acc8[j]);
        *(bf16x8*)(Gout + (size_t)(g * 9 + n) * ldG + cc * 8) = *(const bf16x8*)o8;
    }
}

// ---------------------------------------------------------------------------
// Fused upd-epilogue + LayerNorm:
//   t = P0+P1+ub[c]+vb[c]*S[n]+posU[(n%9)*O+c];  h = gelu(t) + skip(bf16)
//   LN(h) -> outB bf16 (row remap for rows >= rowsplit) or outF fp32
// ---------------------------------------------------------------------------
__global__ __launch_bounds__(256) void ln_kernel(
    const float* __restrict__ P0, const float* __restrict__ P1,
    const float* __restrict__ ub, const float* __restrict__ vb,
    const float* __restrict__ S, const float* __restrict__ posU,
    const ushort* __restrict__ PBs, int ld5,
    const float* __restrict__ gw, const float* __restrict__ bw,
    ushort* outB, int ldoB, int rowsplit, float* outF, int O)
{
    __shared__ float sm[4];
    const int n = blockIdx.x, tid = threadIdx.x;
    const int lane = tid & 63, wid = tid >> 6;
    const float* p0 = P0 + (size_t)n * O;
    const float* p1 = P1 + (size_t)n * O;
    const ushort* sr = PBs + (size_t)n * ld5;
    const float* pu = posU + (size_t)(n % 9) * O;
    const float sv = S[n];
    const int cnt = O >> 8;     // 1 or 2

    float vals[2];
    float sum = 0.f;
#pragma unroll
    for (int i = 0; i < 2; i++) {
        if (i < cnt) {
            int c = tid + 256 * i;
            float t = p0[c] + p1[c] + ub[c] + vb[c] * sv + pu[c];
            vals[i] = gelu_f(t) + b2f(sr[c]);
            sum += vals[i];
        }
    }
#pragma unroll
    for (int off = 32; off; off >>= 1) sum += __shfl_down(sum, off, 64);
    if (lane == 0) sm[wid] = sum;
    __syncthreads();
    const float mu = (sm[0] + sm[1] + sm[2] + sm[3]) / (float)O;
    __syncthreads();

    float var = 0.f;
#pragma unroll
    for (int i = 0; i < 2; i++) {
        if (i < cnt) { float d = vals[i] - mu; var += d * d; }
    }
#pragma unroll
    for (int off = 32; off; off >>= 1) var += __shfl_down(var, off, 64);
    if (lane == 0) sm[wid] = var;
    __syncthreads();
    const float rstd = rsqrtf((sm[0] + sm[1] + sm[2] + sm[3]) / (float)O + 1e-5f);

    int orow = n, coloff = 0;
    if (n >= rowsplit) { orow = n - rowsplit; coloff = 256; }
#pragma unroll
    for (int i = 0; i < 2; i++) {
        if (i < cnt) {
            int c = tid + 256 * i;
            float v = (vals[i] - mu) * rstd * gw[c] + bw[c];
            if (outB) outB[(size_t)orow * ldoB + coloff + c] = f2b(v);
            if (outF) outF[(size_t)n * O + c] = v;
        }
    }
}

// ---------------------------------------------------------------------------
// prep: concat biases, pos tables (posPB/posU), vb, pw2 bf16 copies
// ---------------------------------------------------------------------------
__global__ void prep_kernel(
    const float* __restrict__ pw1_b1, const float* __restrict__ att1_b1, const float* __restrict__ skip_b1,
    const float* __restrict__ pw1_b2, const float* __restrict__ att1_b2, const float* __restrict__ skip_b2,
    const float* __restrict__ pos_table,
    const float* __restrict__ s1_pw1, const float* __restrict__ s1_att, const float* __restrict__ s1_skp,
    const float* __restrict__ s2_pw1, const float* __restrict__ s2_att, const float* __restrict__ s2_skp,
    const float* __restrict__ pw2_b1, const float* __restrict__ upd_w1,
    const float* __restrict__ pw2_b2, const float* __restrict__ upd_w2,
    const float* __restrict__ pw2_w1, const float* __restrict__ pw2_w2,
    float* biasC1, float* biasC2,
    float* posPB1, float* posPB2, float* posU1, float* posU2,
    float* vb1, float* vb2, ushort* pw2f1, ushort* pw2f2)
{
    int i = blockIdx.x * 256 + threadIdx.x;
    if (i < 1280) {
        float v;
        if (i < 256) v = pw1_b1[i];
        else if (i < 512) v = 0.f;
        else if (i < 768) v = att1_b1[i - 512];
        else if (i < 1024) v = 0.f;
        else v = skip_b1[i - 1024];
        biasC1[i] = v;
        return;
    }
    i -= 1280;
    if (i < 2560) {
        float v;
        if (i < 512) v = pw1_b2[i];
        else if (i < 1024) v = 0.f;
        else if (i < 1536) v = att1_b2[i - 1024];
        else if (i < 2048) v = 0.f;
        else v = skip_b2[i - 2048];
        biasC2[i] = v;
        return;
    }
    i -= 2560;
    if (i < 9 * 1280) {   // posPB1[r][n]
        int r = i / 1280, n = i - r * 1280;
        int sec = n >> 8, c = n & 255;
        const float* src; int row0;
        if (sec == 0) { src = s1_pw1; row0 = 256; }
        else if (sec == 1) { src = s1_pw1; row0 = 576; }
        else if (sec == 2) { src = s1_att; row0 = 512; }
        else if (sec == 3) { src = s1_att; row0 = 576; }
        else { src = s1_skp; row0 = 256; }
        float a = 0.f;
        for (int k = 0; k < 64; k++) a += pos_table[r * 64 + k] * src[(size_t)(row0 + k) * 256 + c];
        posPB1[i] = a;
        return;
    }
    i -= 9 * 1280;
    if (i < 9 * 2560) {   // posPB2[r][n]
        int r = i / 2560, n = i - r * 2560;
        int sec = n >> 9, c = n & 511;
        const float* src; int row0;
        if (sec == 0) { src = s2_pw1; row0 = 512; }
        else if (sec == 1) { src = s2_pw1; row0 = 1088; }
        else if (sec == 2) { src = s2_att; row0 = 1024; }
        else if (sec == 3) { src = s2_att; row0 = 1088; }
        else { src = s2_skp; row0 = 512; }
        float a = 0.f;
        for (int k = 0; k < 64; k++) a += pos_table[r * 64 + k] * src[(size_t)(row0 + k) * 512 + c];
        posPB2[i] = a;
        return;
    }
    i -= 9 * 2560;
    if (i < 9 * 256) {    // posU1
        int r = i >> 8, c = i & 255;
        float a = 0.f;
        for (int k = 0; k < 64; k++) a += pos_table[r * 64 + k] * upd_w1[(size_t)(256 + k) * 256 + c];
        posU1[i] = a;
        return;
    }
    i -= 9 * 256;
    if (i < 9 * 512) {    // posU2
        int r = i >> 9, c = i & 511;
        float a = 0.f;
        for (int k = 0; k < 64; k++) a += pos_table[r * 64 + k] * upd_w2[(size_t)(512 + k) * 512 + c];
        posU2[i] = a;
        return;
    }
    i -= 9 * 512;
    if (i < 256) {        // vb1[n] = sum_j pw2_b1[j] * upd_w1[(320+j)][n]
        float a = 0.f;
        for (int j = 0; j < 256; j++) a += pw2_b1[j] * upd_w1[(size_t)(320 + j) * 256 + i];
        vb1[i] = a;
        return;
    }
    i -= 256;
    if (i < 512) {        // vb2
        float a = 0.f;
        for (int j = 0; j < 512; j++) a += pw2_b2[j] * upd_w2[(size_t)(576 + j) * 512 + i];
        vb2[i] = a;
        return;
    }
    i -= 512;
    if (i < 256 * 256) { pw2f1[i] = f2b(pw2_w1[i]); return; }
    i -= 256 * 256;
    if (i < 512 * 512) { pw2f2[i] = f2b(pw2_w2[i]); return; }
}

// ---------------------------------------------------------------------------
// head: pool(9 rows) + cls1 (gelu) + cls2, 4 graphs per block
// ---------------------------------------------------------------------------
__global__ __launch_bounds__(256) void head_kernel(
    const float* __restrict__ h2,
    const float* __restrict__ cls1_w, const float* __restrict__ cls1_b,
    const float* __restrict__ cls2_w, const float* __restrict__ cls2_b,
    float* __restrict__ out)
{
    __shared__ float pooled[4][512];
    __shared__ float hid[4][256];
    const int b = blockIdx.x, tid = threadIdx.x;

    for (int idx = tid; idx < 4 * 512; idx += 256) {
        int gi = idx >> 9, c = idx & 511;
        const float* base = h2 + (size_t)((b * 4 + gi) * 9) * 512 + c;
        float s = 0.f;
#pragma unroll
        for (int k = 0; k < NPG; k++) s += base[(size_t)k * 512];
        pooled[gi][c] = s;
    }
    __syncthreads();

    {
        float acc[4] = {0.f, 0.f, 0.f, 0.f};
        for (int c = 0; c < 512; c++) {
            float w = cls1_w[(size_t)c * 256 + tid];
#pragma unroll
            for (int gi = 0; gi < 4; gi++) acc[gi] += pooled[gi][c] * w;
        }
        float bb = cls1_b[tid];
#pragma unroll
        for (int gi = 0; gi < 4; gi++) hid[gi][tid] = gelu_f(acc[gi] + bb);
    }
    __syncthreads();

    {
        int gi = tid >> 6, lane = tid & 63;
        float p = 0.f;
#pragma unroll
        for (int i = 0; i < 4; i++) p += hid[gi][lane + 64 * i] * cls2_w[lane + 64 * i];
#pragma unroll
        for (int off = 32; off; off >>= 1) p += __shfl_down(p, off, 64);
        if (lane == 0) out[b * 4 + gi] = p + cls2_b[0];
    }
}

// ---------------------------------------------------------------------------
// Host side
// ---------------------------------------------------------------------------
static inline void mg(hipStream_t st, int M, int N, int K,
                      const ushort* A, int lda, const ushort* Wt, int ldw,
                      const float* bias1, const float* prow, int ldp,
                      float* outF, ushort* outB, int ldo,
                      int nz, long partStride)
{
    dim3 grid(N / 128, M / 128, nz);
    mgemm<<<grid, dim3(256), 0, st>>>(A, lda, Wt, ldw, bias1, prow, ldp,
                                      outF, outB, ldo, partStride, K);
}

extern "C" void kernel_launch(void* const* d_in, const int* in_sizes, int n_in,
                              void* d_out, int out_size, void* d_ws, size_t ws_size,
                              hipStream_t stream)
{
    (void)in_sizes; (void)n_in; (void)out_size; (void)ws_size;
    const float* feat_low   = (const float*)d_in[0];
    const float* feat_high  = (const float*)d_in[1];
    const float* pos_table  = (const float*)d_in[4];
    const float* proj_low_w  = (const float*)d_in[5];
    const float* proj_low_b  = (const float*)d_in[6];
    const float* proj_high_w = (const float*)d_in[7];
    const float* proj_high_b = (const float*)d_in[8];
    const float* cls1_w = (const float*)d_in[37];
    const float* cls1_b = (const float*)d_in[38];
    const float* cls2_w = (const float*)d_in[39];
    const float* cls2_b = (const float*)d_in[40];
    float* out = (float*)d_out;

    const float* s1_pw1 = (const float*)d_in[9];
    const float* s1_att = (const float*)d_in[13];
    const float* s1_upd = (const float*)d_in[17];
    const float* s1_skp = (const float*)d_in[21];
    const float* s2_pw1 = (const float*)d_in[23];
    const float* s2_att = (const float*)d_in[27];
    const float* s2_upd = (const float*)d_in[31];
    const float* s2_skp = (const float*)d_in[35];

    const float* att2_w1 = (const float*)d_in[15];
    const float* upd_b1  = (const float*)d_in[18];
    const float* ln_g1   = (const float*)d_in[19];
    const float* ln_b1   = (const float*)d_in[20];
    const float* att2_w2 = (const float*)d_in[29];
    const float* upd_b2  = (const float*)d_in[32];
    const float* ln_g2   = (const float*)d_in[33];
    const float* ln_b2   = (const float*)d_in[34];

    // ---- workspace layout (256B aligned) ----
    char* base = (char*)d_ws;
    size_t cur = 0;
    auto alloc = [&](size_t bytes) { void* p = base + cur; cur += (bytes + 255) & ~(size_t)255; return p; };
    void*   PBreg = alloc((size_t)NN * 2560 * 2);   // PB (s1: 18432x1280, s2: 9216x2560); featB alias
    ushort* PB    = (ushort*)PBreg;
    ushort* featB = (ushort*)PBreg;
    void*   IX1reg = alloc((size_t)NN2 * 512 * 2);  // ixa1 bf16; h2 fp32 alias (disjoint in time)
    ushort* ixa1  = (ushort*)IX1reg;
    float*  h2    = (float*)IX1reg;
    ushort* ixa2  = (ushort*)alloc((size_t)NN * 1024 * 2);
    float*  PT    = (float*)alloc((size_t)4 * NN * 256 * 4);  // split-K partials (37.7 MB)
    float*  S     = (float*)alloc((size_t)NN2 * 4);
    float*  biasC1 = (float*)alloc(1280 * 4);
    float*  biasC2 = (float*)alloc(2560 * 4);
    float*  posPB1 = (float*)alloc(9 * 1280 * 4);
    float*  posPB2 = (float*)alloc(9 * 2560 * 4);
    float*  posU1  = (float*)alloc(9 * 256 * 4);
    float*  posU2  = (float*)alloc(9 * 512 * 4);
    float*  vb1   = (float*)alloc(256 * 4);
    float*  vb2   = (float*)alloc(512 * 4);
    ushort* wbuf  = (ushort*)alloc((size_t)3400000 * 2);

    // ---- weight transpose jobs (x-parts only; pos handled via prow tables) ----
    TJobsArg ja;
    long woff[16];
    {
        struct J { const float* s; int K, N, off0, ldo; long sz; };
        J js[NJOBS] = {
            {proj_low_w,  512, 256, 0, 512, 512L * 256},     // 0 projL
            {proj_high_w, 1024, 256, 0, 1024, 1024L * 256},  // 1 projH
            {s1_pw1, 256, 256, 0, 256, 256L * 256},          // 2 big5-1: pw1d
            {s1_pw1, 256, 256, 320, 256, 256L * 256},        // 3 pw1s
            {s1_att, 256, 256, 0, 256, 256L * 256},          // 4 attd
            {s1_att, 256, 256, 256, 256, 256L * 256},        // 5 atts
            {s1_skp, 256, 256, 0, 256, 256L * 256},          // 6 skip
            {s1_upd, 256, 256, 0, 512, 512L * 256},          // 7 updW1 (x cols)
            {s1_upd, 256, 256, 320, 256, 256L * 256},        // 8 updbT1 (aggr rows)
            {s2_pw1, 512, 512, 0, 512, 512L * 512},          // 9 big5-2: pw1d
            {s2_pw1, 512, 512, 576, 512, 512L * 512},        // 10 pw1s
            {s2_att, 512, 512, 0, 512, 512L * 512},          // 11 attd
            {s2_att, 512, 512, 512, 512, 512L * 512},        // 12 atts
            {s2_skp, 512, 512, 0, 512, 512L * 512},          // 13 skip
            {s2_upd, 512, 512, 0, 1024, 1024L * 512},        // 14 updW2 (x cols)
            {s2_upd, 512, 512, 576, 512, 512L * 512},        // 15 updbT2
        };
        long off = 0;
        for (int i = 0; i < NJOBS; i++) {
            ja.src[i] = js[i].s; ja.K[i] = js[i].K; ja.N[i] = js[i].N;
            ja.off0[i] = js[i].off0; ja.ldo[i] = js[i].ldo;
            ja.dst[i] = off; woff[i] = off;
            off += js[i].sz;
        }
    }
    // pw2 bf16 buffers appended after tw jobs
    long pw2off1 = 0, pw2off2 = 0;
    {
        long off = 0;
        for (int i = 0; i < NJOBS; i++) off += ja.K[i] ? 0 : 0;   // (woff already has ends)
        off = woff[15] + 512L * 512;
        pw2off1 = off; off += 256L * 256;
        pw2off2 = off;
    }
    tw_kernel<<<dim3(256, NJOBS), dim3(256), 0, stream>>>(ja, wbuf);

    ushort* wBig5_1 = wbuf + woff[2];
    ushort* updW1   = wbuf + woff[7];
    ushort* updbT1  = wbuf + woff[8];
    ushort* wBig5_2 = wbuf + woff[9];
    ushort* updW2   = wbuf + woff[14];
    ushort* updbT2  = wbuf + woff[15];
    ushort* pw2f1   = wbuf + pw2off1;
    ushort* pw2f2   = wbuf + pw2off2;

    // ---- prep ----
    {
        int tot = 1280 + 2560 + 9 * 1280 + 9 * 2560 + 9 * 256 + 9 * 512
                + 256 + 512 + 256 * 256 + 512 * 512;
        prep_kernel<<<dim3((tot + 255) / 256), dim3(256), 0, stream>>>(
            (const float*)d_in[10], (const float*)d_in[14], (const float*)d_in[22],
            (const float*)d_in[24], (const float*)d_in[28], (const float*)d_in[36],
            pos_table,
            s1_pw1, s1_att, s1_skp, s2_pw1, s2_att, s2_skp,
            (const float*)d_in[12], s1_upd, (const float*)d_in[26], s2_upd,
            (const float*)d_in[11], (const float*)d_in[25],
            biasC1, biasC2, posPB1, posPB2, posU1, posU2, vb1, vb2, pw2f1, pw2f2);
    }

    // ---- Wcomb = pw2 @ updb, transposed into updW G-columns ----
    mg(stream, 256, 256, 256, updbT1, 256, pw2f1, 256, 0, 0, 0, 0, updW1 + 256, 512, 1, 0);
    mg(stream, 512, 512, 512, updbT2, 512, pw2f2, 512, 0, 0, 0, 0, updW2 + 512, 1024, 1, 0);

    // ---- projections (split-K z=2, partials in PT, reduce to ixa1) ----
    f2b_kernel<<<dim3(NN * 512 / 4 / 256), dim3(256), 0, stream>>>(feat_low, featB, NN * 512 / 4);
    f2b_kernel<<<dim3(NN * 1024 / 4 / 256), dim3(256), 0, stream>>>(
        feat_high, featB + (size_t)NN * 512, NN * 1024 / 4);
    mg(stream, NN, 256, 256, featB, 512, wbuf + woff[0], 512, 0, 0, 0,
       PT, 0, 256, 2, (long)NN * 256);
    mg(stream, NN, 256, 512, featB + (size_t)NN * 512, 1024, wbuf + woff[1], 1024, 0, 0, 0,
       PT + (size_t)2 * NN * 256, 0, 256, 2, (long)NN * 256);
    pjred_kernel<<<dim3(NN2 * 64 / 256), dim3(256), 0, stream>>>(PT, proj_low_b, proj_high_b, ixa1);

    // ---- stage 1 (batched, M = 18432) ----
    mg(stream, NN2, 1280, 256, ixa1, 512, wBig5_1, 256, biasC1, posPB1, 1280, 0, PB, 1280, 1, 0);
    edge_kernel<<<dim3(2 * NUM_GRAPHS), dim3(256), 0, stream>>>(
        PB, att2_w1, ixa1 + 256, 512, S, 256, 5);
    mg(stream, NN2, 256, 256, ixa1, 512, updW1, 512, 0, 0, 0, PT, 0, 256, 2, (long)NN2 * 256);
    ln_kernel<<<dim3(NN2), dim3(256), 0, stream>>>(
        PT, PT + (size_t)NN2 * 256, upd_b1, vb1, S, posU1,
        PB + 4 * 256, 1280, ln_g1, ln_b1, ixa2, 1024, NN, 0, 256);

    // ---- stage 2 ----
    mg(stream, NN, 2560, 512, ixa2, 1024, wBig5_2, 512, biasC2, posPB2, 2560, 0, PB, 2560, 1, 0);
    edge_kernel<<<dim3(NUM_GRAPHS), dim3(256), 0, stream>>>(
        PB, att2_w2, ixa2 + 512, 1024, S, 512, 6);
    mg(stream, NN, 512, 512, ixa2, 1024, updW2, 1024, 0, 0, 0, PT, 0, 512, 2, (long)NN * 512);
    ln_kernel<<<dim3(NN), dim3(256), 0, stream>>>(
        PT, PT + (size_t)NN * 512, upd_b2, vb2, S, posU2,
        PB + 4 * 512, 2560, ln_g2, ln_b2, 0, 0, 1 << 30, h2, 512);

    // ---- head ----
    head_kernel<<<dim3(NUM_GRAPHS / 4), dim3(256), 0, stream>>>(h2, cls1_w, cls1_b, cls2_w, cls2_b, out);
}